// Round 13
// baseline (296.613 us; speedup 1.0000x reference)
//
#include <hip/hip_runtime.h>
#include <cstdint>

constexpr int NB  = 2;     // batch
constexpr int NCI = 4;     // conv input channels
constexpr int NHH = 256;   // H
constexpr int NWW = 256;   // W
constexpr int NCT = 1024;  // conv output channels

// ---------------- workspace layout ----------------
constexpr size_t SW1F = 0;            // 48 floats
constexpr size_t U16_BASE_F = 48;     // u16 region starts here
// u16 offsets (relative to wsu):
constexpr size_t GP_U  = 0;           // G'bf [m][b][i][dx][r][258]
constexpr size_t CW_U  = 297216;      // CW_bf [o][40]
constexpr size_t W2T_U = 338176;      // W2T_bf [m][s][h]
constexpr size_t QU_O  = 350464;      // Q  bf16 [bn][o][xsp]
constexpr size_t KU_O  = 874752;      // K  bf16 [bn][o][xsp]
constexpr size_t VT_O  = 1399040;     // V^T bf16 [bn][xsp][o]

typedef __attribute__((ext_vector_type(8))) short bf16x8;
typedef __attribute__((ext_vector_type(4))) float f32x4;

__device__ __forceinline__ uint16_t f2bf(float x) {
  uint32_t u = __float_as_uint(x);
  return (uint16_t)((u + 0x7FFFu + ((u >> 16) & 1u)) >> 16);   // RNE
}
__device__ __forceinline__ uint32_t pk2bf(float a, float b) {  // lo=bf(a), hi=bf(b)
  const uint32_t au = __float_as_uint(a) + 0x8000u;
  const uint32_t bu = __float_as_uint(b) + 0x8000u;
  return __builtin_amdgcn_perm(bu, au, 0x07060302u);
}
__device__ __forceinline__ float sigmoid_f(float v) {
  return __builtin_amdgcn_rcpf(1.0f + __expf(-v));
}

// K1: G'bf[m][b][i][dx][r][1+h] = bf16( sum_w x_pad[b,i,h,w+dx-1] * W1_m[w,r] )
// REP>1 instances are idempotent probes (rewrite identical values).
template <int REP>
__global__ __launch_bounds__(64) void k1_G(
    const float* __restrict__ x,
    const float* __restrict__ qW1, const float* __restrict__ kW1,
    const float* __restrict__ vW1,
    const float* __restrict__ conv_w,
    const float* __restrict__ qW2, const float* __restrict__ kW2,
    const float* __restrict__ vW2,
    float* __restrict__ wsf, uint16_t* __restrict__ wsu) {
  const int tid = threadIdx.x;
  const int NBLK = 3 * NB * NCI * (NHH / 4);   // 1536
  int bid = blockIdx.x;

  if (bid >= NBLK + 3 + 64) {                  // W2T_bf prep (3 blocks)
    const int m = bid - (NBLK + 3 + 64);
    const float* W2 = (m == 0) ? qW2 : (m == 1) ? kW2 : vW2;
    for (int u = 0; u < 64; ++u) {
      const int idx = tid * 64 + u;            // 4096 = 16 s x 256 h
      const int s = idx >> 8, h = idx & 255;
      wsu[W2T_U + (size_t)m * 4096 + s * 256 + h] = f2bf(W2[h * 16 + s]);
    }
    return;
  }
  if (bid >= NBLK + 3) {                       // CW_bf prep (64 blocks x 16 o)
    const int p = bid - (NBLK + 3);
    const int o = p * 16 + (tid >> 2);
    const int ks = (tid & 3) * 10;
    for (int u = 0; u < 10; ++u) {
      const int k = ks + u;
      wsu[CW_U + (size_t)o * 40 + k] = (k < 36) ? f2bf(conv_w[o * 36 + k]) : (uint16_t)0;
    }
    return;
  }
  if (bid >= NBLK) {                           // sw1 column sums
    int m = bid - NBLK;
    if (tid < 16) {
      const float* W1 = (m == 0) ? qW1 : (m == 1) ? kW1 : vW1;
      float s = 0.f;
      for (int w = 0; w < 256; ++w) s += W1[w * 16 + tid];
      wsf[SW1F + m * 16 + tid] = s;
    }
    return;
  }

  const int m  = bid / (NB * NCI * (NHH / 4));
  int rem      = bid % (NB * NCI * (NHH / 4));
  const int b  = rem / (NCI * (NHH / 4));
  rem          = rem % (NCI * (NHH / 4));
  const int i  = rem / (NHH / 4);
  const int h0 = (rem % (NHH / 4)) * 4;
  const int mb = m * NB + b;

  const float* W1 = (m == 0) ? qW1 : (m == 1) ? kW1 : vW1;

  __shared__ float W1l[16 * 260];
  __shared__ float xlb[4][260];

  #pragma unroll 1
  for (int rep = 0; rep < REP; ++rep) {
    for (int idx4 = tid; idx4 < 1024; idx4 += 64) {
      const float4 t = ((const float4*)W1)[idx4];
      const int w = idx4 >> 2, r0 = (idx4 & 3) * 4;
      W1l[(r0 + 0) * 260 + w] = t.x;
      W1l[(r0 + 1) * 260 + w] = t.y;
      W1l[(r0 + 2) * 260 + w] = t.z;
      W1l[(r0 + 3) * 260 + w] = t.w;
    }
    const float* xbase = x + ((size_t)(b * NCI + i) * NHH + h0) * NWW;
    for (int idx = tid; idx < 4 * 256; idx += 64) {
      const int rr = idx >> 8, w = idx & 255;
      xlb[rr][1 + w] = xbase[rr * NWW + w];
    }
    if (tid < 4) {
      xlb[tid][0] = 0.f; xlb[tid][257] = 0.f; xlb[tid][258] = 0.f; xlb[tid][259] = 0.f;
    }
    __syncthreads();

    // pad rows hp=0 and hp=257 (zeros)
    if (h0 == 0 && tid < 48) {
      const int dxp = tid >> 4, rp = tid & 15;
      wsu[GP_U + ((size_t)((mb * 4 + i) * 3 + dxp) * 16 + rp) * 258 + 0] = 0;
    }
    if (h0 == 252 && tid < 48) {
      const int dxp = tid >> 4, rp = tid & 15;
      wsu[GP_U + ((size_t)((mb * 4 + i) * 3 + dxp) * 16 + rp) * 258 + 257] = 0;
    }

    const int wc = tid >> 4, r = tid & 15;
    const int w0 = wc * 64;
    const size_t gb0 = GP_U + ((size_t)((mb * 4 + i) * 3 + 0) * 16 + r) * 258;

    #pragma unroll
    for (int rr = 0; rr < 4; ++rr) {
      const float* xl = xlb[rr];
      float a0 = 0.f, a1 = 0.f, a2 = 0.f;
      float4 cur = *(const float4*)&xl[w0];
      #pragma unroll 4
      for (int w = w0; w < w0 + 64; w += 4) {
        const float4 nxt = *(const float4*)&xl[w + 4];
        const float4 w1  = *(const float4*)&W1l[r * 260 + w];
        a0 += w1.x * cur.x + w1.y * cur.y + w1.z * cur.z + w1.w * cur.w;
        a1 += w1.x * cur.y + w1.y * cur.z + w1.z * cur.w + w1.w * nxt.x;
        a2 += w1.x * cur.z + w1.y * cur.w + w1.z * nxt.x + w1.w * nxt.y;
        cur = nxt;
      }
      a0 += __shfl_xor(a0, 16, 64); a0 += __shfl_xor(a0, 32, 64);
      a1 += __shfl_xor(a1, 16, 64); a1 += __shfl_xor(a1, 32, 64);
      a2 += __shfl_xor(a2, 16, 64); a2 += __shfl_xor(a2, 32, 64);
      if (wc == 0) {
        const int hp = 1 + h0 + rr;
        wsu[gb0 + hp]        = f2bf(a0);   // dx = 0
        wsu[gb0 + 4128 + hp] = f2bf(a1);   // dx = 1
        wsu[gb0 + 8256 + hp] = f2bf(a2);   // dx = 2
      }
    }
    __syncthreads();
  }
}

// K2 (MFMA): bf16 epilogue: Q,K [bn][o][xsp], V^T [bn][xsp][o].
// REP>1 instances are idempotent probes.
template <int REP>
__global__ __launch_bounds__(256, 4) void k2_mfma(
    const uint16_t* __restrict__ gp, const uint16_t* __restrict__ cwbf,
    const uint16_t* __restrict__ w2t,
    const float* __restrict__ conv_b,
    const float* __restrict__ qb1, const float* __restrict__ kb1, const float* __restrict__ vb1,
    const float* __restrict__ qb2, const float* __restrict__ kb2, const float* __restrict__ vb2,
    const float* __restrict__ wsf, uint16_t* __restrict__ wsu) {
  const int tid = threadIdx.x;
  const int bid = blockIdx.x;
  const int r  = bid & 15;
  const int og = (bid >> 4) & 15;
  const int mb = bid >> 8;            // 0..5
  const int m  = mb >> 1, b = mb & 1;

  const int wv  = tid >> 6;
  const int l   = tid & 63;
  const int l15 = l & 15;
  const int lg  = l >> 4;

  __shared__ uint16_t GS[256 * 40];     // [h][k]
  __shared__ uint16_t y1l[4][16 * 72];  // per-wave [o16][h64+8pad]

  const float* b1 = (m == 0) ? qb1 : (m == 1) ? kb1 : vb1;
  const float* b2 = (m == 0) ? qb2 : (m == 1) ? kb2 : vb2;
  const int o_blk = og * 64 + wv * 16;

  #pragma unroll 1
  for (int rep = 0; rep < REP; ++rep) {
    {
      const int h = tid;
      uint16_t* gsrow = &GS[h * 40];
      #pragma unroll
      for (int i = 0; i < 4; ++i) {
        #pragma unroll
        for (int dx = 0; dx < 3; ++dx) {
          const uint16_t* g = gp + ((size_t)((mb * 4 + i) * 3 + dx) * 16 + r) * 258 + h;
          gsrow[i * 9 + 0 * 3 + dx] = g[0];
          gsrow[i * 9 + 1 * 3 + dx] = g[1];
          gsrow[i * 9 + 2 * 3 + dx] = g[2];
        }
      }
      gsrow[36] = 0; gsrow[37] = 0; gsrow[38] = 0; gsrow[39] = 0;
    }
    __syncthreads();

    const uint16_t* cwrow = cwbf + (size_t)(o_blk + l15) * 40;
    bf16x8 cw0 = *(const bf16x8*)(cwrow + lg * 8);
    bf16x8 cw1 = {0,0,0,0,0,0,0,0};
    if (lg == 0) cw1 = *(const bf16x8*)(cwrow + 32);

    const uint16_t* w2row = w2t + (size_t)m * 4096 + (size_t)l15 * 256 + lg * 8;
    bf16x8 w2f0 = *(const bf16x8*)(w2row + 0 * 32);
    bf16x8 w2f1 = *(const bf16x8*)(w2row + 1 * 32);
    bf16x8 w2f2 = *(const bf16x8*)(w2row + 2 * 32);
    bf16x8 w2f3 = *(const bf16x8*)(w2row + 3 * 32);
    bf16x8 w2f4 = *(const bf16x8*)(w2row + 4 * 32);
    bf16x8 w2f5 = *(const bf16x8*)(w2row + 5 * 32);
    bf16x8 w2f6 = *(const bf16x8*)(w2row + 6 * 32);
    bf16x8 w2f7 = *(const bf16x8*)(w2row + 7 * 32);

    const float sw1r = wsf[SW1F + m * 16 + r];
    const float b1r  = b1[r];
    const float cbv  = conv_b[o_blk + l15];
    const float bias1 = cbv * sw1r + b1r;
    const float b2v  = b2[l15];

    uint16_t* yw = &y1l[wv][0];
    f32x4 acc2 = {0.f, 0.f, 0.f, 0.f};

    #pragma unroll
    for (int cc = 0; cc < 4; ++cc) {
      #pragma unroll
      for (int ct = 0; ct < 4; ++ct) {
        const uint16_t* arow = &GS[(cc * 64 + ct * 16 + l15) * 40];
        bf16x8 a0 = *(const bf16x8*)(arow + lg * 8);
        bf16x8 a1 = {0,0,0,0,0,0,0,0};
        if (lg == 0) a1 = *(const bf16x8*)(arow + 32);
        f32x4 d = {0.f, 0.f, 0.f, 0.f};
        d = __builtin_amdgcn_mfma_f32_16x16x32_bf16(a0, cw0, d, 0, 0, 0);
        d = __builtin_amdgcn_mfma_f32_16x16x32_bf16(a1, cw1, d, 0, 0, 0);
        const float y0 = sigmoid_f(d[0] + bias1);
        const float y1 = sigmoid_f(d[1] + bias1);
        const float y2 = sigmoid_f(d[2] + bias1);
        const float y3 = sigmoid_f(d[3] + bias1);
        uint32_t* yd = (uint32_t*)&yw[l15 * 72 + ct * 16 + lg * 4];
        yd[0] = pk2bf(y0, y1);
        yd[1] = pk2bf(y2, y3);
      }
      {
        const uint16_t* yrow = &yw[l15 * 72 + lg * 8];
        bf16x8 ya0 = *(const bf16x8*)(yrow + 0);
        bf16x8 ya1 = *(const bf16x8*)(yrow + 32);
        if (cc == 0) {
          acc2 = __builtin_amdgcn_mfma_f32_16x16x32_bf16(ya0, w2f0, acc2, 0, 0, 0);
          acc2 = __builtin_amdgcn_mfma_f32_16x16x32_bf16(ya1, w2f1, acc2, 0, 0, 0);
        } else if (cc == 1) {
          acc2 = __builtin_amdgcn_mfma_f32_16x16x32_bf16(ya0, w2f2, acc2, 0, 0, 0);
          acc2 = __builtin_amdgcn_mfma_f32_16x16x32_bf16(ya1, w2f3, acc2, 0, 0, 0);
        } else if (cc == 2) {
          acc2 = __builtin_amdgcn_mfma_f32_16x16x32_bf16(ya0, w2f4, acc2, 0, 0, 0);
          acc2 = __builtin_amdgcn_mfma_f32_16x16x32_bf16(ya1, w2f5, acc2, 0, 0, 0);
        } else {
          acc2 = __builtin_amdgcn_mfma_f32_16x16x32_bf16(ya0, w2f6, acc2, 0, 0, 0);
          acc2 = __builtin_amdgcn_mfma_f32_16x16x32_bf16(ya1, w2f7, acc2, 0, 0, 0);
        }
      }
    }

    // epilogue: y2 = sigmoid(acc2 + b2) -> bf16 q/k/vT
    const int s   = l15;
    const int n   = (s & 1) * 2 + (r & 1);
    const int xsp = (s >> 1) * 8 + (r >> 1);
    const int bn  = b * 4 + n;
    uint16_t* qk = wsu + ((m == 0) ? QU_O : KU_O);
    uint16_t* vT = wsu + VT_O;
    #pragma unroll
    for (int p = 0; p < 4; ++p) {
      const int o = o_blk + lg * 4 + p;
      const uint16_t y2 = f2bf(sigmoid_f(acc2[p] + b2v));
      if (m == 2) vT[((size_t)bn * 64 + xsp) * 1024 + o] = y2;
      else        qk[((size_t)bn * 1024 + o) * 64 + xsp] = y2;
    }
    __syncthreads();
  }
}

// K3 (fused flash + in-block merge; VGPR-capped). REP>1 = idempotent probe.
template <int REP>
__global__ __launch_bounds__(512, 4) void k3_attn(
    const uint16_t* __restrict__ qu, const uint16_t* __restrict__ ku,
    const uint16_t* __restrict__ vtu, const float* __restrict__ temp,
    float* __restrict__ out) {
  const int tid = threadIdx.x;
  const int wv  = tid >> 6;
  const int l   = tid & 63;
  const int l15 = l & 15, lg = l >> 4;
  const int bid = blockIdx.x;
  const int bn = bid & 7;          // XCD pin
  const int ct = bid >> 3;
  const int cbase = ct * 16;
  const float tsc2 = temp[bn & 3] * 1.44269504089f;   // log2(e) folded

  __shared__ __align__(16) char SH[36864];
  uint16_t* pl  = (uint16_t*)SH + wv * 2304;   // per-wave P buffer
  float* poS = (float*)SH;                     // [8 waves][16 c][68] partial O^T
  float* mlS = poS + 8704;                     // [8 waves][32]: 16 m + 16 l

  const uint16_t* qrow = qu + (size_t)(bn * 1024 + cbase + l15) * 64 + lg * 8;
  const bf16x8 qf0 = *(const bf16x8*)(qrow);
  const bf16x8 qf1 = *(const bf16x8*)(qrow + 32);

  const uint16_t* kb = ku  + (size_t)bn * 65536 + lg * 8;
  const uint16_t* vb = vtu + (size_t)bn * 65536 + lg * 8;

  #pragma unroll 1
  for (int rep = 0; rep < REP; ++rep) {
    f32x4 o0 = {0.f,0.f,0.f,0.f}, o1 = o0, o2 = o0, o3 = o0;
    float mrun = -1.0e30f, lrun = 0.f;

    #pragma unroll
    for (int t = 0; t < 2; ++t) {
      const int e0 = wv * 128 + t * 64;

      const uint16_t* kr0 = kb + (size_t)(e0 +  0 + l15) * 64;
      const uint16_t* kr1 = kb + (size_t)(e0 + 16 + l15) * 64;
      const uint16_t* kr2 = kb + (size_t)(e0 + 32 + l15) * 64;
      const uint16_t* kr3 = kb + (size_t)(e0 + 48 + l15) * 64;
      const bf16x8 ka0 = *(const bf16x8*)(kr0);
      const bf16x8 kb0 = *(const bf16x8*)(kr0 + 32);
      const bf16x8 ka1 = *(const bf16x8*)(kr1);
      const bf16x8 kb1_ = *(const bf16x8*)(kr1 + 32);
      const bf16x8 ka2 = *(const bf16x8*)(kr2);
      const bf16x8 kb2_ = *(const bf16x8*)(kr2 + 32);
      const bf16x8 ka3 = *(const bf16x8*)(kr3);
      const bf16x8 kb3_ = *(const bf16x8*)(kr3 + 32);

      f32x4 s0 = {0.f,0.f,0.f,0.f}, s1 = s0, s2 = s0, s3 = s0;
      s0 = __builtin_amdgcn_mfma_f32_16x16x32_bf16(ka0, qf0, s0, 0,0,0);
      s0 = __builtin_amdgcn_mfma_f32_16x16x32_bf16(kb0, qf1, s0, 0,0,0);
      s1 = __builtin_amdgcn_mfma_f32_16x16x32_bf16(ka1, qf0, s1, 0,0,0);
      s1 = __builtin_amdgcn_mfma_f32_16x16x32_bf16(kb1_, qf1, s1, 0,0,0);
      s2 = __builtin_amdgcn_mfma_f32_16x16x32_bf16(ka2, qf0, s2, 0,0,0);
      s2 = __builtin_amdgcn_mfma_f32_16x16x32_bf16(kb2_, qf1, s2, 0,0,0);
      s3 = __builtin_amdgcn_mfma_f32_16x16x32_bf16(ka3, qf0, s3, 0,0,0);
      s3 = __builtin_amdgcn_mfma_f32_16x16x32_bf16(kb3_, qf1, s3, 0,0,0);

      const uint16_t* vr0 = vb + (size_t)( 0 + l15) * 1024 + e0;
      const uint16_t* vr1 = vb + (size_t)(16 + l15) * 1024 + e0;
      const uint16_t* vr2 = vb + (size_t)(32 + l15) * 1024 + e0;
      const uint16_t* vr3 = vb + (size_t)(48 + l15) * 1024 + e0;
      const bf16x8 v0a = *(const bf16x8*)(vr0);
      const bf16x8 v0b = *(const bf16x8*)(vr0 + 32);
      const bf16x8 v1a = *(const bf16x8*)(vr1);
      const bf16x8 v1b = *(const bf16x8*)(vr1 + 32);
      const bf16x8 v2a = *(const bf16x8*)(vr2);
      const bf16x8 v2b = *(const bf16x8*)(vr2 + 32);
      const bf16x8 v3a = *(const bf16x8*)(vr3);
      const bf16x8 v3b = *(const bf16x8*)(vr3 + 32);

      #pragma unroll
      for (int p = 0; p < 4; ++p) {
        s0[p] *= tsc2; s1[p] *= tsc2; s2[p] *= tsc2; s3[p] *= tsc2;
      }
      float t0 = fmaxf(fmaxf(s0[0], s0[1]), fmaxf(s0[2], s0[3]));
      float t1 = fmaxf(fmaxf(s1[0], s1[1]), fmaxf(s1[2], s1[3]));
      float t2 = fmaxf(fmaxf(s2[0], s2[1]), fmaxf(s2[2], s2[3]));
      float t3 = fmaxf(fmaxf(s3[0], s3[1]), fmaxf(s3[2], s3[3]));
      float tmax = fmaxf(fmaxf(t0, t1), fmaxf(t2, t3));
      tmax = fmaxf(tmax, __shfl_xor(tmax, 16, 64));
      tmax = fmaxf(tmax, __shfl_xor(tmax, 32, 64));
      const float mnew = fmaxf(mrun, tmax);
      const float scl  = exp2f(mrun - mnew);
      float psum = 0.f;
      #pragma unroll
      for (int p = 0; p < 4; ++p) { s0[p] = exp2f(s0[p] - mnew); psum += s0[p]; }
      #pragma unroll
      for (int p = 0; p < 4; ++p) { s1[p] = exp2f(s1[p] - mnew); psum += s1[p]; }
      #pragma unroll
      for (int p = 0; p < 4; ++p) { s2[p] = exp2f(s2[p] - mnew); psum += s2[p]; }
      #pragma unroll
      for (int p = 0; p < 4; ++p) { s3[p] = exp2f(s3[p] - mnew); psum += s3[p]; }
      psum += __shfl_xor(psum, 16, 64);
      psum += __shfl_xor(psum, 32, 64);
      lrun = lrun * scl + psum;
      mrun = mnew;

      {
        uint32_t* p0w = (uint32_t*)&pl[l15 * 72 +  0 + lg * 4];
        uint32_t* p1w = (uint32_t*)&pl[l15 * 72 + 16 + lg * 4];
        uint32_t* p2w = (uint32_t*)&pl[l15 * 72 + 32 + lg * 4];
        uint32_t* p3w = (uint32_t*)&pl[l15 * 72 + 48 + lg * 4];
        p0w[0] = pk2bf(s0[0], s0[1]); p0w[1] = pk2bf(s0[2], s0[3]);
        p1w[0] = pk2bf(s1[0], s1[1]); p1w[1] = pk2bf(s1[2], s1[3]);
        p2w[0] = pk2bf(s2[0], s2[1]); p2w[1] = pk2bf(s2[2], s2[3]);
        p3w[0] = pk2bf(s3[0], s3[1]); p3w[1] = pk2bf(s3[2], s3[3]);
      }

      #pragma unroll
      for (int p = 0; p < 4; ++p) {
        o0[p] *= scl; o1[p] *= scl; o2[p] *= scl; o3[p] *= scl;
      }

      {
        const bf16x8 pb0 = *(const bf16x8*)&pl[l15 * 72 +  0 + lg * 8];
        const bf16x8 pb1 = *(const bf16x8*)&pl[l15 * 72 + 32 + lg * 8];
        o0 = __builtin_amdgcn_mfma_f32_16x16x32_bf16(v0a, pb0, o0, 0,0,0);
        o0 = __builtin_amdgcn_mfma_f32_16x16x32_bf16(v0b, pb1, o0, 0,0,0);
        o1 = __builtin_amdgcn_mfma_f32_16x16x32_bf16(v1a, pb0, o1, 0,0,0);
        o1 = __builtin_amdgcn_mfma_f32_16x16x32_bf16(v1b, pb1, o1, 0,0,0);
        o2 = __builtin_amdgcn_mfma_f32_16x16x32_bf16(v2a, pb0, o2, 0,0,0);
        o2 = __builtin_amdgcn_mfma_f32_16x16x32_bf16(v2b, pb1, o2, 0,0,0);
        o3 = __builtin_amdgcn_mfma_f32_16x16x32_bf16(v3a, pb0, o3, 0,0,0);
        o3 = __builtin_amdgcn_mfma_f32_16x16x32_bf16(v3b, pb1, o3, 0,0,0);
      }
    }

    // ---- all waves done with P buffers before aliasing them ----
    __syncthreads();

    {
      float* po = poS + wv * 1088 + l15 * 68 + lg * 4;
      *(f32x4*)&po[ 0] = o0;
      *(f32x4*)&po[16] = o1;
      *(f32x4*)&po[32] = o2;
      *(f32x4*)&po[48] = o3;
      if (lg == 0) {
        mlS[wv * 32 + l15]      = mrun;
        mlS[wv * 32 + 16 + l15] = lrun;
      }
    }
    __syncthreads();

    {
      const int c  = tid >> 5;
      const int x2 = (tid & 31) * 2;

      float m0 = mlS[0 * 32 + c], m1 = mlS[1 * 32 + c];
      float m2 = mlS[2 * 32 + c], m3 = mlS[3 * 32 + c];
      float m4 = mlS[4 * 32 + c], m5 = mlS[5 * 32 + c];
      float m6 = mlS[6 * 32 + c], m7 = mlS[7 * 32 + c];
      const float M = fmaxf(fmaxf(fmaxf(m0, m1), fmaxf(m2, m3)),
                            fmaxf(fmaxf(m4, m5), fmaxf(m6, m7)));
      const float c0 = exp2f(m0 - M), c1 = exp2f(m1 - M);
      const float c2 = exp2f(m2 - M), c3 = exp2f(m3 - M);
      const float c4 = exp2f(m4 - M), c5 = exp2f(m5 - M);
      const float c6 = exp2f(m6 - M), c7 = exp2f(m7 - M);
      const float L = c0 * mlS[0 * 32 + 16 + c] + c1 * mlS[1 * 32 + 16 + c]
                    + c2 * mlS[2 * 32 + 16 + c] + c3 * mlS[3 * 32 + 16 + c]
                    + c4 * mlS[4 * 32 + 16 + c] + c5 * mlS[5 * 32 + 16 + c]
                    + c6 * mlS[6 * 32 + 16 + c] + c7 * mlS[7 * 32 + 16 + c];
      const float rl = __builtin_amdgcn_rcpf(L);

      const float* pb = poS + c * 68 + x2;
      float a0 = 0.f, a1 = 0.f;
      a0 += c0 * pb[0 * 1088]; a1 += c0 * pb[0 * 1088 + 1];
      a0 += c1 * pb[1 * 1088]; a1 += c1 * pb[1 * 1088 + 1];
      a0 += c2 * pb[2 * 1088]; a1 += c2 * pb[2 * 1088 + 1];
      a0 += c3 * pb[3 * 1088]; a1 += c3 * pb[3 * 1088 + 1];
      a0 += c4 * pb[4 * 1088]; a1 += c4 * pb[4 * 1088 + 1];
      a0 += c5 * pb[5 * 1088]; a1 += c5 * pb[5 * 1088 + 1];
      a0 += c6 * pb[6 * 1088]; a1 += c6 * pb[6 * 1088 + 1];
      a0 += c7 * pb[7 * 1088]; a1 += c7 * pb[7 * 1088 + 1];

      const int C = cbase + c;
      float* ob = out + ((size_t)bn * 256 + (C >> 2)) * 256 + (C & 3) * 64 + x2;
      ob[0] = a0 * rl;
      ob[1] = a1 * rl;
    }
    __syncthreads();   // merge reads of poS complete before next rep's P writes
  }
}

extern "C" void kernel_launch(void* const* d_in, const int* in_sizes, int n_in,
                              void* d_out, int out_size, void* d_ws, size_t ws_size,
                              hipStream_t stream) {
  (void)in_sizes; (void)n_in; (void)out_size; (void)ws_size;
  const float* x      = (const float*)d_in[0];
  const float* conv_w = (const float*)d_in[1];
  const float* conv_b = (const float*)d_in[2];
  const float* qW1 = (const float*)d_in[3];
  const float* qb1 = (const float*)d_in[4];
  const float* qW2 = (const float*)d_in[5];
  const float* qb2 = (const float*)d_in[6];
  const float* kW1 = (const float*)d_in[7];
  const float* kb1 = (const float*)d_in[8];
  const float* kW2 = (const float*)d_in[9];
  const float* kb2 = (const float*)d_in[10];
  const float* vW1 = (const float*)d_in[11];
  const float* vb1 = (const float*)d_in[12];
  const float* vW2 = (const float*)d_in[13];
  const float* vb2 = (const float*)d_in[14];
  const float* temp = (const float*)d_in[15];
  float* wsf = (float*)d_ws;
  uint16_t* wsu = (uint16_t*)(wsf + U16_BASE_F);
  float* out = (float*)d_out;

  // ---- real pipeline ----
  k1_G<1><<<dim3(1606), dim3(64), 0, stream>>>(x, qW1, kW1, vW1,
      conv_w, qW2, kW2, vW2, wsf, wsu);
  k2_mfma<1><<<dim3(1536), dim3(256), 0, stream>>>(
      wsu + GP_U, wsu + CW_U, wsu + W2T_U, conv_b,
      qb1, kb1, vb1, qb2, kb2, vb2, wsf, wsu);
  k3_attn<1><<<dim3(512), dim3(512), 0, stream>>>(
      wsu + QU_O, wsu + KU_O, wsu + VT_O, temp, out);

  // ---- x8 idempotent probes (diagnostic round: rewrite identical values,
  //      rise above the 41us fill rows so rocprof top-5 shows per-kernel
  //      counters; removed next round) ----
  k1_G<8><<<dim3(1606), dim3(64), 0, stream>>>(x, qW1, kW1, vW1,
      conv_w, qW2, kW2, vW2, wsf, wsu);
  k2_mfma<8><<<dim3(1536), dim3(256), 0, stream>>>(
      wsu + GP_U, wsu + CW_U, wsu + W2T_U, conv_b,
      qb1, kb1, vb1, qb2, kb2, vb2, wsf, wsu);
  k3_attn<8><<<dim3(512), dim3(512), 0, stream>>>(
      wsu + QU_O, wsu + KU_O, wsu + VT_O, temp, out);
}

// Round 14
// 49.422 us; speedup vs baseline: 6.0017x; 6.0017x over previous
//
#include <hip/hip_runtime.h>
#include <cstdint>

constexpr int NB  = 2;     // batch
constexpr int NCI = 4;     // conv input channels
constexpr int NHH = 256;   // H
constexpr int NWW = 256;   // W
constexpr int NCT = 1024;  // conv output channels

// ---------------- workspace layout ----------------
constexpr size_t SW1F = 0;            // 48 floats
constexpr size_t U16_BASE_F = 48;     // u16 region starts here
// u16 offsets (relative to wsu):
constexpr size_t GP_U  = 0;           // G'bf [m][b][i][dx][r][258]
constexpr size_t CW_U  = 297216;      // CW_bf [o][40]
constexpr size_t W2T_U = 338176;      // W2T_bf [m][s][h]
constexpr size_t QU_O  = 350464;      // Q  bf16 [bn][o][xsp]
constexpr size_t KU_O  = 874752;      // K  bf16 [bn][o][xsp]
constexpr size_t VT_O  = 1399040;     // V^T bf16 [bn][xsp][o]

typedef __attribute__((ext_vector_type(8))) short bf16x8;
typedef __attribute__((ext_vector_type(4))) float f32x4;

__device__ __forceinline__ uint16_t f2bf(float x) {
  uint32_t u = __float_as_uint(x);
  return (uint16_t)((u + 0x7FFFu + ((u >> 16) & 1u)) >> 16);   // RNE
}
__device__ __forceinline__ uint32_t pk2bf(float a, float b) {  // lo=bf(a), hi=bf(b)
  const uint32_t au = __float_as_uint(a) + 0x8000u;
  const uint32_t bu = __float_as_uint(b) + 0x8000u;
  return __builtin_amdgcn_perm(bu, au, 0x07060302u);
}
__device__ __forceinline__ float sigmoid_f(float v) {
  return __builtin_amdgcn_rcpf(1.0f + __expf(-v));
}

// K1: G'bf[m][b][i][dx][r][1+h] = bf16( sum_w x_pad[b,i,h,w+dx-1] * W1_m[w,r] )
// plus sw1 sums, plus CW_bf / W2T_bf prep blocks.  (unchanged)
__global__ __launch_bounds__(64) void k1_G(
    const float* __restrict__ x,
    const float* __restrict__ qW1, const float* __restrict__ kW1,
    const float* __restrict__ vW1,
    const float* __restrict__ conv_w,
    const float* __restrict__ qW2, const float* __restrict__ kW2,
    const float* __restrict__ vW2,
    float* __restrict__ wsf, uint16_t* __restrict__ wsu) {
  const int tid = threadIdx.x;
  const int NBLK = 3 * NB * NCI * (NHH / 4);   // 1536
  int bid = blockIdx.x;

  if (bid >= NBLK + 3 + 64) {                  // W2T_bf prep (3 blocks)
    const int m = bid - (NBLK + 3 + 64);
    const float* W2 = (m == 0) ? qW2 : (m == 1) ? kW2 : vW2;
    for (int u = 0; u < 64; ++u) {
      const int idx = tid * 64 + u;            // 4096 = 16 s x 256 h
      const int s = idx >> 8, h = idx & 255;
      wsu[W2T_U + (size_t)m * 4096 + s * 256 + h] = f2bf(W2[h * 16 + s]);
    }
    return;
  }
  if (bid >= NBLK + 3) {                       // CW_bf prep (64 blocks x 16 o)
    const int p = bid - (NBLK + 3);
    const int o = p * 16 + (tid >> 2);
    const int ks = (tid & 3) * 10;
    for (int u = 0; u < 10; ++u) {
      const int k = ks + u;
      wsu[CW_U + (size_t)o * 40 + k] = (k < 36) ? f2bf(conv_w[o * 36 + k]) : (uint16_t)0;
    }
    return;
  }
  if (bid >= NBLK) {                           // sw1 column sums
    int m = bid - NBLK;
    if (tid < 16) {
      const float* W1 = (m == 0) ? qW1 : (m == 1) ? kW1 : vW1;
      float s = 0.f;
      for (int w = 0; w < 256; ++w) s += W1[w * 16 + tid];
      wsf[SW1F + m * 16 + tid] = s;
    }
    return;
  }

  const int m  = bid / (NB * NCI * (NHH / 4));
  int rem      = bid % (NB * NCI * (NHH / 4));
  const int b  = rem / (NCI * (NHH / 4));
  rem          = rem % (NCI * (NHH / 4));
  const int i  = rem / (NHH / 4);
  const int h0 = (rem % (NHH / 4)) * 4;
  const int mb = m * NB + b;

  const float* W1 = (m == 0) ? qW1 : (m == 1) ? kW1 : vW1;

  __shared__ float W1l[16 * 260];
  __shared__ float xlb[4][260];

  for (int idx4 = tid; idx4 < 1024; idx4 += 64) {
    const float4 t = ((const float4*)W1)[idx4];
    const int w = idx4 >> 2, r0 = (idx4 & 3) * 4;
    W1l[(r0 + 0) * 260 + w] = t.x;
    W1l[(r0 + 1) * 260 + w] = t.y;
    W1l[(r0 + 2) * 260 + w] = t.z;
    W1l[(r0 + 3) * 260 + w] = t.w;
  }
  const float* xbase = x + ((size_t)(b * NCI + i) * NHH + h0) * NWW;
  for (int idx = tid; idx < 4 * 256; idx += 64) {
    const int rr = idx >> 8, w = idx & 255;
    xlb[rr][1 + w] = xbase[rr * NWW + w];
  }
  if (tid < 4) {
    xlb[tid][0] = 0.f; xlb[tid][257] = 0.f; xlb[tid][258] = 0.f; xlb[tid][259] = 0.f;
  }
  __syncthreads();

  // pad rows hp=0 and hp=257 (zeros)
  if (h0 == 0 && tid < 48) {
    const int dxp = tid >> 4, rp = tid & 15;
    wsu[GP_U + ((size_t)((mb * 4 + i) * 3 + dxp) * 16 + rp) * 258 + 0] = 0;
  }
  if (h0 == 252 && tid < 48) {
    const int dxp = tid >> 4, rp = tid & 15;
    wsu[GP_U + ((size_t)((mb * 4 + i) * 3 + dxp) * 16 + rp) * 258 + 257] = 0;
  }

  const int wc = tid >> 4, r = tid & 15;
  const int w0 = wc * 64;
  const size_t gb0 = GP_U + ((size_t)((mb * 4 + i) * 3 + 0) * 16 + r) * 258;

  #pragma unroll
  for (int rr = 0; rr < 4; ++rr) {
    const float* xl = xlb[rr];
    float a0 = 0.f, a1 = 0.f, a2 = 0.f;
    float4 cur = *(const float4*)&xl[w0];
    #pragma unroll 4
    for (int w = w0; w < w0 + 64; w += 4) {
      const float4 nxt = *(const float4*)&xl[w + 4];
      const float4 w1  = *(const float4*)&W1l[r * 260 + w];
      a0 += w1.x * cur.x + w1.y * cur.y + w1.z * cur.z + w1.w * cur.w;
      a1 += w1.x * cur.y + w1.y * cur.z + w1.z * cur.w + w1.w * nxt.x;
      a2 += w1.x * cur.z + w1.y * cur.w + w1.z * nxt.x + w1.w * nxt.y;
      cur = nxt;
    }
    a0 += __shfl_xor(a0, 16, 64); a0 += __shfl_xor(a0, 32, 64);
    a1 += __shfl_xor(a1, 16, 64); a1 += __shfl_xor(a1, 32, 64);
    a2 += __shfl_xor(a2, 16, 64); a2 += __shfl_xor(a2, 32, 64);
    if (wc == 0) {
      const int hp = 1 + h0 + rr;
      wsu[gb0 + hp]        = f2bf(a0);   // dx = 0
      wsu[gb0 + 4128 + hp] = f2bf(a1);   // dx = 1
      wsu[gb0 + 8256 + hp] = f2bf(a2);   // dx = 2
    }
  }
}

// K2 (MFMA): bf16 epilogue: Q,K [bn][o][xsp], V^T [bn][xsp][o].  (unchanged)
__global__ __launch_bounds__(256, 4) void k2_mfma(
    const uint16_t* __restrict__ gp, const uint16_t* __restrict__ cwbf,
    const uint16_t* __restrict__ w2t,
    const float* __restrict__ conv_b,
    const float* __restrict__ qb1, const float* __restrict__ kb1, const float* __restrict__ vb1,
    const float* __restrict__ qb2, const float* __restrict__ kb2, const float* __restrict__ vb2,
    const float* __restrict__ wsf, uint16_t* __restrict__ wsu) {
  const int tid = threadIdx.x;
  const int bid = blockIdx.x;
  const int r  = bid & 15;
  const int og = (bid >> 4) & 15;
  const int mb = bid >> 8;            // 0..5
  const int m  = mb >> 1, b = mb & 1;

  const int wv  = tid >> 6;
  const int l   = tid & 63;
  const int l15 = l & 15;
  const int lg  = l >> 4;

  __shared__ uint16_t GS[256 * 40];     // [h][k]
  __shared__ uint16_t y1l[4][16 * 72];  // per-wave [o16][h64+8pad]

  {
    const int h = tid;
    uint16_t* gsrow = &GS[h * 40];
    #pragma unroll
    for (int i = 0; i < 4; ++i) {
      #pragma unroll
      for (int dx = 0; dx < 3; ++dx) {
        const uint16_t* g = gp + ((size_t)((mb * 4 + i) * 3 + dx) * 16 + r) * 258 + h;
        gsrow[i * 9 + 0 * 3 + dx] = g[0];
        gsrow[i * 9 + 1 * 3 + dx] = g[1];
        gsrow[i * 9 + 2 * 3 + dx] = g[2];
      }
    }
    gsrow[36] = 0; gsrow[37] = 0; gsrow[38] = 0; gsrow[39] = 0;
  }
  __syncthreads();

  const float* b1 = (m == 0) ? qb1 : (m == 1) ? kb1 : vb1;
  const float* b2 = (m == 0) ? qb2 : (m == 1) ? kb2 : vb2;

  const int o_blk = og * 64 + wv * 16;

  const uint16_t* cwrow = cwbf + (size_t)(o_blk + l15) * 40;
  bf16x8 cw0 = *(const bf16x8*)(cwrow + lg * 8);
  bf16x8 cw1 = {0,0,0,0,0,0,0,0};
  if (lg == 0) cw1 = *(const bf16x8*)(cwrow + 32);

  const uint16_t* w2row = w2t + (size_t)m * 4096 + (size_t)l15 * 256 + lg * 8;
  bf16x8 w2f0 = *(const bf16x8*)(w2row + 0 * 32);
  bf16x8 w2f1 = *(const bf16x8*)(w2row + 1 * 32);
  bf16x8 w2f2 = *(const bf16x8*)(w2row + 2 * 32);
  bf16x8 w2f3 = *(const bf16x8*)(w2row + 3 * 32);
  bf16x8 w2f4 = *(const bf16x8*)(w2row + 4 * 32);
  bf16x8 w2f5 = *(const bf16x8*)(w2row + 5 * 32);
  bf16x8 w2f6 = *(const bf16x8*)(w2row + 6 * 32);
  bf16x8 w2f7 = *(const bf16x8*)(w2row + 7 * 32);

  const float sw1r = wsf[SW1F + m * 16 + r];
  const float b1r  = b1[r];
  const float cbv  = conv_b[o_blk + l15];
  const float bias1 = cbv * sw1r + b1r;
  const float b2v  = b2[l15];

  uint16_t* yw = &y1l[wv][0];
  f32x4 acc2 = {0.f, 0.f, 0.f, 0.f};

  #pragma unroll
  for (int cc = 0; cc < 4; ++cc) {
    #pragma unroll
    for (int ct = 0; ct < 4; ++ct) {
      const uint16_t* arow = &GS[(cc * 64 + ct * 16 + l15) * 40];
      bf16x8 a0 = *(const bf16x8*)(arow + lg * 8);
      bf16x8 a1 = {0,0,0,0,0,0,0,0};
      if (lg == 0) a1 = *(const bf16x8*)(arow + 32);
      f32x4 d = {0.f, 0.f, 0.f, 0.f};
      d = __builtin_amdgcn_mfma_f32_16x16x32_bf16(a0, cw0, d, 0, 0, 0);
      d = __builtin_amdgcn_mfma_f32_16x16x32_bf16(a1, cw1, d, 0, 0, 0);
      const float y0 = sigmoid_f(d[0] + bias1);
      const float y1 = sigmoid_f(d[1] + bias1);
      const float y2 = sigmoid_f(d[2] + bias1);
      const float y3 = sigmoid_f(d[3] + bias1);
      uint32_t* yd = (uint32_t*)&yw[l15 * 72 + ct * 16 + lg * 4];
      yd[0] = pk2bf(y0, y1);
      yd[1] = pk2bf(y2, y3);
    }
    {
      const uint16_t* yrow = &yw[l15 * 72 + lg * 8];
      bf16x8 ya0 = *(const bf16x8*)(yrow + 0);
      bf16x8 ya1 = *(const bf16x8*)(yrow + 32);
      if (cc == 0) {
        acc2 = __builtin_amdgcn_mfma_f32_16x16x32_bf16(ya0, w2f0, acc2, 0, 0, 0);
        acc2 = __builtin_amdgcn_mfma_f32_16x16x32_bf16(ya1, w2f1, acc2, 0, 0, 0);
      } else if (cc == 1) {
        acc2 = __builtin_amdgcn_mfma_f32_16x16x32_bf16(ya0, w2f2, acc2, 0, 0, 0);
        acc2 = __builtin_amdgcn_mfma_f32_16x16x32_bf16(ya1, w2f3, acc2, 0, 0, 0);
      } else if (cc == 2) {
        acc2 = __builtin_amdgcn_mfma_f32_16x16x32_bf16(ya0, w2f4, acc2, 0, 0, 0);
        acc2 = __builtin_amdgcn_mfma_f32_16x16x32_bf16(ya1, w2f5, acc2, 0, 0, 0);
      } else {
        acc2 = __builtin_amdgcn_mfma_f32_16x16x32_bf16(ya0, w2f6, acc2, 0, 0, 0);
        acc2 = __builtin_amdgcn_mfma_f32_16x16x32_bf16(ya1, w2f7, acc2, 0, 0, 0);
      }
    }
  }

  // epilogue: y2 = sigmoid(acc2 + b2) -> bf16 q/k/vT
  const int s   = l15;
  const int n   = (s & 1) * 2 + (r & 1);
  const int xsp = (s >> 1) * 8 + (r >> 1);
  const int bn  = b * 4 + n;
  uint16_t* qk = wsu + ((m == 0) ? QU_O : KU_O);
  uint16_t* vT = wsu + VT_O;
  #pragma unroll
  for (int p = 0; p < 4; ++p) {
    const int o = o_blk + lg * 4 + p;
    const uint16_t y2 = f2bf(sigmoid_f(acc2[p] + b2v));
    if (m == 2) vT[((size_t)bn * 64 + xsp) * 1024 + o] = y2;
    else        qk[((size_t)bn * 1024 + o) * 64 + xsp] = y2;
  }
}

// K3 (fused flash + in-block merge; VGPR-capped; CHUNKED XCD pin):
// grid 512; bn = bid>>6 — under chunked dispatch (consecutive bids fill the
// same XCD), all 64 blocks of one bn (258 KB K+V working set) land on one
// XCD's 4MB L2 at 2 blocks/CU. (R10's bid&7 assumed round-robin; R13's
// FETCH counters showed 38 MB/pass L2-miss traffic = pin was a no-op.)
__global__ __launch_bounds__(512, 4) void k3_attn(
    const uint16_t* __restrict__ qu, const uint16_t* __restrict__ ku,
    const uint16_t* __restrict__ vtu, const float* __restrict__ temp,
    float* __restrict__ out) {
  const int tid = threadIdx.x;
  const int wv  = tid >> 6;
  const int l   = tid & 63;
  const int l15 = l & 15, lg = l >> 4;
  const int bid = blockIdx.x;
  const int bn = bid >> 6;         // chunked XCD pin
  const int ct = bid & 63;
  const int cbase = ct * 16;
  const float tsc2 = temp[bn & 3] * 1.44269504089f;   // log2(e) folded

  __shared__ __align__(16) char SH[36864];
  uint16_t* pl  = (uint16_t*)SH + wv * 2304;   // per-wave P buffer
  float* poS = (float*)SH;                     // [8 waves][16 c][68] partial O^T
  float* mlS = poS + 8704;                     // [8 waves][32]: 16 m + 16 l

  const uint16_t* qrow = qu + (size_t)(bn * 1024 + cbase + l15) * 64 + lg * 8;
  const bf16x8 qf0 = *(const bf16x8*)(qrow);
  const bf16x8 qf1 = *(const bf16x8*)(qrow + 32);

  const uint16_t* kb = ku  + (size_t)bn * 65536 + lg * 8;
  const uint16_t* vb = vtu + (size_t)bn * 65536 + lg * 8;

  f32x4 o0 = {0.f,0.f,0.f,0.f}, o1 = o0, o2 = o0, o3 = o0;
  float mrun = -1.0e30f, lrun = 0.f;

  #pragma unroll
  for (int t = 0; t < 2; ++t) {
    const int e0 = wv * 128 + t * 64;

    // ---- K frags for this tile (32 VGPR, die after QK) ----
    const uint16_t* kr0 = kb + (size_t)(e0 +  0 + l15) * 64;
    const uint16_t* kr1 = kb + (size_t)(e0 + 16 + l15) * 64;
    const uint16_t* kr2 = kb + (size_t)(e0 + 32 + l15) * 64;
    const uint16_t* kr3 = kb + (size_t)(e0 + 48 + l15) * 64;
    const bf16x8 ka0 = *(const bf16x8*)(kr0);
    const bf16x8 kb0 = *(const bf16x8*)(kr0 + 32);
    const bf16x8 ka1 = *(const bf16x8*)(kr1);
    const bf16x8 kb1_ = *(const bf16x8*)(kr1 + 32);
    const bf16x8 ka2 = *(const bf16x8*)(kr2);
    const bf16x8 kb2_ = *(const bf16x8*)(kr2 + 32);
    const bf16x8 ka3 = *(const bf16x8*)(kr3);
    const bf16x8 kb3_ = *(const bf16x8*)(kr3 + 32);

    f32x4 s0 = {0.f,0.f,0.f,0.f}, s1 = s0, s2 = s0, s3 = s0;
    s0 = __builtin_amdgcn_mfma_f32_16x16x32_bf16(ka0, qf0, s0, 0,0,0);
    s0 = __builtin_amdgcn_mfma_f32_16x16x32_bf16(kb0, qf1, s0, 0,0,0);
    s1 = __builtin_amdgcn_mfma_f32_16x16x32_bf16(ka1, qf0, s1, 0,0,0);
    s1 = __builtin_amdgcn_mfma_f32_16x16x32_bf16(kb1_, qf1, s1, 0,0,0);
    s2 = __builtin_amdgcn_mfma_f32_16x16x32_bf16(ka2, qf0, s2, 0,0,0);
    s2 = __builtin_amdgcn_mfma_f32_16x16x32_bf16(kb2_, qf1, s2, 0,0,0);
    s3 = __builtin_amdgcn_mfma_f32_16x16x32_bf16(ka3, qf0, s3, 0,0,0);
    s3 = __builtin_amdgcn_mfma_f32_16x16x32_bf16(kb3_, qf1, s3, 0,0,0);

    // ---- V frags issue NOW (latency hides under softmax; reuse K's regs) ----
    const uint16_t* vr0 = vb + (size_t)( 0 + l15) * 1024 + e0;
    const uint16_t* vr1 = vb + (size_t)(16 + l15) * 1024 + e0;
    const uint16_t* vr2 = vb + (size_t)(32 + l15) * 1024 + e0;
    const uint16_t* vr3 = vb + (size_t)(48 + l15) * 1024 + e0;
    const bf16x8 v0a = *(const bf16x8*)(vr0);
    const bf16x8 v0b = *(const bf16x8*)(vr0 + 32);
    const bf16x8 v1a = *(const bf16x8*)(vr1);
    const bf16x8 v1b = *(const bf16x8*)(vr1 + 32);
    const bf16x8 v2a = *(const bf16x8*)(vr2);
    const bf16x8 v2b = *(const bf16x8*)(vr2 + 32);
    const bf16x8 v3a = *(const bf16x8*)(vr3);
    const bf16x8 v3b = *(const bf16x8*)(vr3 + 32);

    // ---- softmax in exp2 domain (per c = l15 column; lanes {l15+16g}) ----
    #pragma unroll
    for (int p = 0; p < 4; ++p) {
      s0[p] *= tsc2; s1[p] *= tsc2; s2[p] *= tsc2; s3[p] *= tsc2;
    }
    float t0 = fmaxf(fmaxf(s0[0], s0[1]), fmaxf(s0[2], s0[3]));
    float t1 = fmaxf(fmaxf(s1[0], s1[1]), fmaxf(s1[2], s1[3]));
    float t2 = fmaxf(fmaxf(s2[0], s2[1]), fmaxf(s2[2], s2[3]));
    float t3 = fmaxf(fmaxf(s3[0], s3[1]), fmaxf(s3[2], s3[3]));
    float tmax = fmaxf(fmaxf(t0, t1), fmaxf(t2, t3));
    tmax = fmaxf(tmax, __shfl_xor(tmax, 16, 64));
    tmax = fmaxf(tmax, __shfl_xor(tmax, 32, 64));
    const float mnew = fmaxf(mrun, tmax);
    const float scl  = exp2f(mrun - mnew);
    float psum = 0.f;
    #pragma unroll
    for (int p = 0; p < 4; ++p) { s0[p] = exp2f(s0[p] - mnew); psum += s0[p]; }
    #pragma unroll
    for (int p = 0; p < 4; ++p) { s1[p] = exp2f(s1[p] - mnew); psum += s1[p]; }
    #pragma unroll
    for (int p = 0; p < 4; ++p) { s2[p] = exp2f(s2[p] - mnew); psum += s2[p]; }
    #pragma unroll
    for (int p = 0; p < 4; ++p) { s3[p] = exp2f(s3[p] - mnew); psum += s3[p]; }
    psum += __shfl_xor(psum, 16, 64);
    psum += __shfl_xor(psum, 32, 64);
    lrun = lrun * scl + psum;
    mrun = mnew;

    // ---- pack P -> LDS [c][e] ----
    {
      uint32_t* p0w = (uint32_t*)&pl[l15 * 72 +  0 + lg * 4];
      uint32_t* p1w = (uint32_t*)&pl[l15 * 72 + 16 + lg * 4];
      uint32_t* p2w = (uint32_t*)&pl[l15 * 72 + 32 + lg * 4];
      uint32_t* p3w = (uint32_t*)&pl[l15 * 72 + 48 + lg * 4];
      p0w[0] = pk2bf(s0[0], s0[1]); p0w[1] = pk2bf(s0[2], s0[3]);
      p1w[0] = pk2bf(s1[0], s1[1]); p1w[1] = pk2bf(s1[2], s1[3]);
      p2w[0] = pk2bf(s2[0], s2[1]); p2w[1] = pk2bf(s2[2], s2[3]);
      p3w[0] = pk2bf(s3[0], s3[1]); p3w[1] = pk2bf(s3[2], s3[3]);
    }

    // ---- rescale O^T by scl (lane-local) ----
    #pragma unroll
    for (int p = 0; p < 4; ++p) {
      o0[p] *= scl; o1[p] *= scl; o2[p] *= scl; o3[p] *= scl;
    }

    // ---- PV: O^T[x][c] += sum_e V^T[x][e] P[e][c] ----
    {
      const bf16x8 pb0 = *(const bf16x8*)&pl[l15 * 72 +  0 + lg * 8];
      const bf16x8 pb1 = *(const bf16x8*)&pl[l15 * 72 + 32 + lg * 8];
      o0 = __builtin_amdgcn_mfma_f32_16x16x32_bf16(v0a, pb0, o0, 0,0,0);
      o0 = __builtin_amdgcn_mfma_f32_16x16x32_bf16(v0b, pb1, o0, 0,0,0);
      o1 = __builtin_amdgcn_mfma_f32_16x16x32_bf16(v1a, pb0, o1, 0,0,0);
      o1 = __builtin_amdgcn_mfma_f32_16x16x32_bf16(v1b, pb1, o1, 0,0,0);
      o2 = __builtin_amdgcn_mfma_f32_16x16x32_bf16(v2a, pb0, o2, 0,0,0);
      o2 = __builtin_amdgcn_mfma_f32_16x16x32_bf16(v2b, pb1, o2, 0,0,0);
      o3 = __builtin_amdgcn_mfma_f32_16x16x32_bf16(v3a, pb0, o3, 0,0,0);
      o3 = __builtin_amdgcn_mfma_f32_16x16x32_bf16(v3b, pb1, o3, 0,0,0);
    }
  }

  // ---- all waves done with P buffers before aliasing them ----
  __syncthreads();

  {
    float* po = poS + wv * 1088 + l15 * 68 + lg * 4;
    *(f32x4*)&po[ 0] = o0;
    *(f32x4*)&po[16] = o1;
    *(f32x4*)&po[32] = o2;
    *(f32x4*)&po[48] = o3;
    if (lg == 0) {
      mlS[wv * 32 + l15]      = mrun;
      mlS[wv * 32 + 16 + l15] = lrun;
    }
  }
  __syncthreads();

  // ---- merge: thread handles (c = tid>>5, x2 = (tid&31)*2, x2+1) ----
  {
    const int c  = tid >> 5;
    const int x2 = (tid & 31) * 2;

    float m0 = mlS[0 * 32 + c], m1 = mlS[1 * 32 + c];
    float m2 = mlS[2 * 32 + c], m3 = mlS[3 * 32 + c];
    float m4 = mlS[4 * 32 + c], m5 = mlS[5 * 32 + c];
    float m6 = mlS[6 * 32 + c], m7 = mlS[7 * 32 + c];
    const float M = fmaxf(fmaxf(fmaxf(m0, m1), fmaxf(m2, m3)),
                          fmaxf(fmaxf(m4, m5), fmaxf(m6, m7)));
    const float c0 = exp2f(m0 - M), c1 = exp2f(m1 - M);
    const float c2 = exp2f(m2 - M), c3 = exp2f(m3 - M);
    const float c4 = exp2f(m4 - M), c5 = exp2f(m5 - M);
    const float c6 = exp2f(m6 - M), c7 = exp2f(m7 - M);
    const float L = c0 * mlS[0 * 32 + 16 + c] + c1 * mlS[1 * 32 + 16 + c]
                  + c2 * mlS[2 * 32 + 16 + c] + c3 * mlS[3 * 32 + 16 + c]
                  + c4 * mlS[4 * 32 + 16 + c] + c5 * mlS[5 * 32 + 16 + c]
                  + c6 * mlS[6 * 32 + 16 + c] + c7 * mlS[7 * 32 + 16 + c];
    const float rl = __builtin_amdgcn_rcpf(L);

    const float* pb = poS + c * 68 + x2;
    float a0 = 0.f, a1 = 0.f;
    a0 += c0 * pb[0 * 1088]; a1 += c0 * pb[0 * 1088 + 1];
    a0 += c1 * pb[1 * 1088]; a1 += c1 * pb[1 * 1088 + 1];
    a0 += c2 * pb[2 * 1088]; a1 += c2 * pb[2 * 1088 + 1];
    a0 += c3 * pb[3 * 1088]; a1 += c3 * pb[3 * 1088 + 1];
    a0 += c4 * pb[4 * 1088]; a1 += c4 * pb[4 * 1088 + 1];
    a0 += c5 * pb[5 * 1088]; a1 += c5 * pb[5 * 1088 + 1];
    a0 += c6 * pb[6 * 1088]; a1 += c6 * pb[6 * 1088 + 1];
    a0 += c7 * pb[7 * 1088]; a1 += c7 * pb[7 * 1088 + 1];

    const int C = cbase + c;
    float* ob = out + ((size_t)bn * 256 + (C >> 2)) * 256 + (C & 3) * 64 + x2;
    ob[0] = a0 * rl;
    ob[1] = a1 * rl;
  }
}

extern "C" void kernel_launch(void* const* d_in, const int* in_sizes, int n_in,
                              void* d_out, int out_size, void* d_ws, size_t ws_size,
                              hipStream_t stream) {
  (void)in_sizes; (void)n_in; (void)out_size; (void)ws_size;
  const float* x      = (const float*)d_in[0];
  const float* conv_w = (const float*)d_in[1];
  const float* conv_b = (const float*)d_in[2];
  const float* qW1 = (const float*)d_in[3];
  const float* qb1 = (const float*)d_in[4];
  const float* qW2 = (const float*)d_in[5];
  const float* qb2 = (const float*)d_in[6];
  const float* kW1 = (const float*)d_in[7];
  const float* kb1 = (const float*)d_in[8];
  const float* kW2 = (const float*)d_in[9];
  const float* kb2 = (const float*)d_in[10];
  const float* vW1 = (const float*)d_in[11];
  const float* vb1 = (const float*)d_in[12];
  const float* vW2 = (const float*)d_in[13];
  const float* vb2 = (const float*)d_in[14];
  const float* temp = (const float*)d_in[15];
  float* wsf = (float*)d_ws;
  uint16_t* wsu = (uint16_t*)(wsf + U16_BASE_F);
  float* out = (float*)d_out;

  k1_G<<<dim3(1606), dim3(64), 0, stream>>>(x, qW1, kW1, vW1,
      conv_w, qW2, kW2, vW2, wsf, wsu);
  k2_mfma<<<dim3(1536), dim3(256), 0, stream>>>(
      wsu + GP_U, wsu + CW_U, wsu + W2T_U, conv_b,
      qb1, kb1, vb1, qb2, kb2, vb2, wsf, wsu);
  k3_attn<<<dim3(512), dim3(512), 0, stream>>>(
      wsu + QU_O, wsu + KU_O, wsu + VT_O, temp, out);
}

// Round 15
// 47.660 us; speedup vs baseline: 6.2236x; 1.0370x over previous
//
#include <hip/hip_runtime.h>
#include <cstdint>

constexpr int NB  = 2;     // batch
constexpr int NCI = 4;     // conv input channels
constexpr int NHH = 256;   // H
constexpr int NWW = 256;   // W
constexpr int NCT = 1024;  // conv output channels

// ---------------- workspace layout ----------------
constexpr size_t SW1F = 0;            // 48 floats
constexpr size_t U16_BASE_F = 48;     // u16 region starts here
// u16 offsets (relative to wsu):
constexpr size_t GP_U  = 0;           // G'bf [m][b][i][dx][r][258]
constexpr size_t CW_U  = 297216;      // CW_bf [o][40]
constexpr size_t W2T_U = 338176;      // W2T_bf [m][s][h]
constexpr size_t QU_O  = 350464;      // Q  bf16 [bn][o][xsp]
constexpr size_t KU_O  = 874752;      // K  bf16 [bn][o][xsp]
constexpr size_t VT_O  = 1399040;     // V^T bf16 [bn][xsp][o]

typedef __attribute__((ext_vector_type(8))) short bf16x8;
typedef __attribute__((ext_vector_type(4))) float f32x4;

__device__ __forceinline__ uint16_t f2bf(float x) {
  uint32_t u = __float_as_uint(x);
  return (uint16_t)((u + 0x7FFFu + ((u >> 16) & 1u)) >> 16);   // RNE
}
__device__ __forceinline__ uint32_t pk2bf(float a, float b) {  // lo=bf(a), hi=bf(b)
  const uint32_t au = __float_as_uint(a) + 0x8000u;
  const uint32_t bu = __float_as_uint(b) + 0x8000u;
  return __builtin_amdgcn_perm(bu, au, 0x07060302u);
}
__device__ __forceinline__ float sigmoid_f(float v) {
  return __builtin_amdgcn_rcpf(1.0f + __expf(-v));
}

// K1: G'bf[m][b][i][dx][r][1+h] = bf16( sum_w x_pad[b,i,h,w+dx-1] * W1_m[w,r] )
// R15: prep blocks parallelized — sw1 was a 16-thread x 256-serial-load
// straggler (~10 us wall tail hidden inside k1; R13's probe didn't amplify
// prep branches so it was invisible in the /8 accounting).
// grid: 1536 (G) + 3 (sw1) + 64 (CW) + 24 (W2T) = 1627, block 64
__global__ __launch_bounds__(64) void k1_G(
    const float* __restrict__ x,
    const float* __restrict__ qW1, const float* __restrict__ kW1,
    const float* __restrict__ vW1,
    const float* __restrict__ conv_w,
    const float* __restrict__ qW2, const float* __restrict__ kW2,
    const float* __restrict__ vW2,
    float* __restrict__ wsf, uint16_t* __restrict__ wsu) {
  const int tid = threadIdx.x;
  const int NBLK = 3 * NB * NCI * (NHH / 4);   // 1536
  int bid = blockIdx.x;

  if (bid >= NBLK + 3 + 64) {                  // W2T_bf prep (24 blocks)
    const int p = bid - (NBLK + 3 + 64);       // 0..23
    const int m = p >> 3;
    const int h0 = (p & 7) * 32;
    const float* W2 = (m == 0) ? qW2 : (m == 1) ? kW2 : vW2;
    const int hh = tid >> 1, part = tid & 1;   // 32 h x 2 halves
    const float* src = W2 + (size_t)(h0 + hh) * 16 + part * 8;
    const float4 a = *(const float4*)(src);
    const float4 b2 = *(const float4*)(src + 4);
    uint16_t* dst = wsu + W2T_U + (size_t)m * 4096 + h0 + hh;
    dst[(part * 8 + 0) * 256] = f2bf(a.x);
    dst[(part * 8 + 1) * 256] = f2bf(a.y);
    dst[(part * 8 + 2) * 256] = f2bf(a.z);
    dst[(part * 8 + 3) * 256] = f2bf(a.w);
    dst[(part * 8 + 4) * 256] = f2bf(b2.x);
    dst[(part * 8 + 5) * 256] = f2bf(b2.y);
    dst[(part * 8 + 6) * 256] = f2bf(b2.z);
    dst[(part * 8 + 7) * 256] = f2bf(b2.w);
    return;
  }
  if (bid >= NBLK + 3) {                       // CW_bf prep (64 blocks x 16 o)
    const int p = bid - (NBLK + 3);
    const int o = p * 16 + (tid >> 2);
    const int ks = (tid & 3) * 10;
    for (int u = 0; u < 10; ++u) {
      const int k = ks + u;
      wsu[CW_U + (size_t)o * 40 + k] = (k < 36) ? f2bf(conv_w[o * 36 + k]) : (uint16_t)0;
    }
    return;
  }
  if (bid >= NBLK) {                           // sw1 column sums (wave-parallel)
    const int m = bid - NBLK;
    const float* W1 = (m == 0) ? qW1 : (m == 1) ? kW1 : vW1;
    const int wc = tid >> 4, r = tid & 15;
    float s = 0.f;
    #pragma unroll 8
    for (int i = 0; i < 64; ++i) s += W1[(wc * 64 + i) * 16 + r];
    s += __shfl_xor(s, 16, 64);
    s += __shfl_xor(s, 32, 64);
    if (tid < 16) wsf[SW1F + m * 16 + tid] = s;
    return;
  }

  const int m  = bid / (NB * NCI * (NHH / 4));
  int rem      = bid % (NB * NCI * (NHH / 4));
  const int b  = rem / (NCI * (NHH / 4));
  rem          = rem % (NCI * (NHH / 4));
  const int i  = rem / (NHH / 4);
  const int h0 = (rem % (NHH / 4)) * 4;
  const int mb = m * NB + b;

  const float* W1 = (m == 0) ? qW1 : (m == 1) ? kW1 : vW1;

  __shared__ float W1l[16 * 260];
  __shared__ float xlb[4][260];

  for (int idx4 = tid; idx4 < 1024; idx4 += 64) {
    const float4 t = ((const float4*)W1)[idx4];
    const int w = idx4 >> 2, r0 = (idx4 & 3) * 4;
    W1l[(r0 + 0) * 260 + w] = t.x;
    W1l[(r0 + 1) * 260 + w] = t.y;
    W1l[(r0 + 2) * 260 + w] = t.z;
    W1l[(r0 + 3) * 260 + w] = t.w;
  }
  const float* xbase = x + ((size_t)(b * NCI + i) * NHH + h0) * NWW;
  for (int idx = tid; idx < 4 * 256; idx += 64) {
    const int rr = idx >> 8, w = idx & 255;
    xlb[rr][1 + w] = xbase[rr * NWW + w];
  }
  if (tid < 4) {
    xlb[tid][0] = 0.f; xlb[tid][257] = 0.f; xlb[tid][258] = 0.f; xlb[tid][259] = 0.f;
  }
  __syncthreads();

  // pad rows hp=0 and hp=257 (zeros)
  if (h0 == 0 && tid < 48) {
    const int dxp = tid >> 4, rp = tid & 15;
    wsu[GP_U + ((size_t)((mb * 4 + i) * 3 + dxp) * 16 + rp) * 258 + 0] = 0;
  }
  if (h0 == 252 && tid < 48) {
    const int dxp = tid >> 4, rp = tid & 15;
    wsu[GP_U + ((size_t)((mb * 4 + i) * 3 + dxp) * 16 + rp) * 258 + 257] = 0;
  }

  const int wc = tid >> 4, r = tid & 15;
  const int w0 = wc * 64;
  const size_t gb0 = GP_U + ((size_t)((mb * 4 + i) * 3 + 0) * 16 + r) * 258;

  #pragma unroll
  for (int rr = 0; rr < 4; ++rr) {
    const float* xl = xlb[rr];
    float a0 = 0.f, a1 = 0.f, a2 = 0.f;
    float4 cur = *(const float4*)&xl[w0];
    #pragma unroll 4
    for (int w = w0; w < w0 + 64; w += 4) {
      const float4 nxt = *(const float4*)&xl[w + 4];
      const float4 w1  = *(const float4*)&W1l[r * 260 + w];
      a0 += w1.x * cur.x + w1.y * cur.y + w1.z * cur.z + w1.w * cur.w;
      a1 += w1.x * cur.y + w1.y * cur.z + w1.z * cur.w + w1.w * nxt.x;
      a2 += w1.x * cur.z + w1.y * cur.w + w1.z * nxt.x + w1.w * nxt.y;
      cur = nxt;
    }
    a0 += __shfl_xor(a0, 16, 64); a0 += __shfl_xor(a0, 32, 64);
    a1 += __shfl_xor(a1, 16, 64); a1 += __shfl_xor(a1, 32, 64);
    a2 += __shfl_xor(a2, 16, 64); a2 += __shfl_xor(a2, 32, 64);
    if (wc == 0) {
      const int hp = 1 + h0 + rr;
      wsu[gb0 + hp]        = f2bf(a0);   // dx = 0
      wsu[gb0 + 4128 + hp] = f2bf(a1);   // dx = 1
      wsu[gb0 + 8256 + hp] = f2bf(a2);   // dx = 2
    }
  }
}

// K2 (MFMA): bf16 epilogue: Q,K [bn][o][xsp], V^T [bn][xsp][o].  (unchanged)
__global__ __launch_bounds__(256, 4) void k2_mfma(
    const uint16_t* __restrict__ gp, const uint16_t* __restrict__ cwbf,
    const uint16_t* __restrict__ w2t,
    const float* __restrict__ conv_b,
    const float* __restrict__ qb1, const float* __restrict__ kb1, const float* __restrict__ vb1,
    const float* __restrict__ qb2, const float* __restrict__ kb2, const float* __restrict__ vb2,
    const float* __restrict__ wsf, uint16_t* __restrict__ wsu) {
  const int tid = threadIdx.x;
  const int bid = blockIdx.x;
  const int r  = bid & 15;
  const int og = (bid >> 4) & 15;
  const int mb = bid >> 8;            // 0..5
  const int m  = mb >> 1, b = mb & 1;

  const int wv  = tid >> 6;
  const int l   = tid & 63;
  const int l15 = l & 15;
  const int lg  = l >> 4;

  __shared__ uint16_t GS[256 * 40];     // [h][k]
  __shared__ uint16_t y1l[4][16 * 72];  // per-wave [o16][h64+8pad]

  {
    const int h = tid;
    uint16_t* gsrow = &GS[h * 40];
    #pragma unroll
    for (int i = 0; i < 4; ++i) {
      #pragma unroll
      for (int dx = 0; dx < 3; ++dx) {
        const uint16_t* g = gp + ((size_t)((mb * 4 + i) * 3 + dx) * 16 + r) * 258 + h;
        gsrow[i * 9 + 0 * 3 + dx] = g[0];
        gsrow[i * 9 + 1 * 3 + dx] = g[1];
        gsrow[i * 9 + 2 * 3 + dx] = g[2];
      }
    }
    gsrow[36] = 0; gsrow[37] = 0; gsrow[38] = 0; gsrow[39] = 0;
  }
  __syncthreads();

  const float* b1 = (m == 0) ? qb1 : (m == 1) ? kb1 : vb1;
  const float* b2 = (m == 0) ? qb2 : (m == 1) ? kb2 : vb2;

  const int o_blk = og * 64 + wv * 16;

  const uint16_t* cwrow = cwbf + (size_t)(o_blk + l15) * 40;
  bf16x8 cw0 = *(const bf16x8*)(cwrow + lg * 8);
  bf16x8 cw1 = {0,0,0,0,0,0,0,0};
  if (lg == 0) cw1 = *(const bf16x8*)(cwrow + 32);

  const uint16_t* w2row = w2t + (size_t)m * 4096 + (size_t)l15 * 256 + lg * 8;
  bf16x8 w2f0 = *(const bf16x8*)(w2row + 0 * 32);
  bf16x8 w2f1 = *(const bf16x8*)(w2row + 1 * 32);
  bf16x8 w2f2 = *(const bf16x8*)(w2row + 2 * 32);
  bf16x8 w2f3 = *(const bf16x8*)(w2row + 3 * 32);
  bf16x8 w2f4 = *(const bf16x8*)(w2row + 4 * 32);
  bf16x8 w2f5 = *(const bf16x8*)(w2row + 5 * 32);
  bf16x8 w2f6 = *(const bf16x8*)(w2row + 6 * 32);
  bf16x8 w2f7 = *(const bf16x8*)(w2row + 7 * 32);

  const float sw1r = wsf[SW1F + m * 16 + r];
  const float b1r  = b1[r];
  const float cbv  = conv_b[o_blk + l15];
  const float bias1 = cbv * sw1r + b1r;
  const float b2v  = b2[l15];

  uint16_t* yw = &y1l[wv][0];
  f32x4 acc2 = {0.f, 0.f, 0.f, 0.f};

  #pragma unroll
  for (int cc = 0; cc < 4; ++cc) {
    #pragma unroll
    for (int ct = 0; ct < 4; ++ct) {
      const uint16_t* arow = &GS[(cc * 64 + ct * 16 + l15) * 40];
      bf16x8 a0 = *(const bf16x8*)(arow + lg * 8);
      bf16x8 a1 = {0,0,0,0,0,0,0,0};
      if (lg == 0) a1 = *(const bf16x8*)(arow + 32);
      f32x4 d = {0.f, 0.f, 0.f, 0.f};
      d = __builtin_amdgcn_mfma_f32_16x16x32_bf16(a0, cw0, d, 0, 0, 0);
      d = __builtin_amdgcn_mfma_f32_16x16x32_bf16(a1, cw1, d, 0, 0, 0);
      const float y0 = sigmoid_f(d[0] + bias1);
      const float y1 = sigmoid_f(d[1] + bias1);
      const float y2 = sigmoid_f(d[2] + bias1);
      const float y3 = sigmoid_f(d[3] + bias1);
      uint32_t* yd = (uint32_t*)&yw[l15 * 72 + ct * 16 + lg * 4];
      yd[0] = pk2bf(y0, y1);
      yd[1] = pk2bf(y2, y3);
    }
    {
      const uint16_t* yrow = &yw[l15 * 72 + lg * 8];
      bf16x8 ya0 = *(const bf16x8*)(yrow + 0);
      bf16x8 ya1 = *(const bf16x8*)(yrow + 32);
      if (cc == 0) {
        acc2 = __builtin_amdgcn_mfma_f32_16x16x32_bf16(ya0, w2f0, acc2, 0, 0, 0);
        acc2 = __builtin_amdgcn_mfma_f32_16x16x32_bf16(ya1, w2f1, acc2, 0, 0, 0);
      } else if (cc == 1) {
        acc2 = __builtin_amdgcn_mfma_f32_16x16x32_bf16(ya0, w2f2, acc2, 0, 0, 0);
        acc2 = __builtin_amdgcn_mfma_f32_16x16x32_bf16(ya1, w2f3, acc2, 0, 0, 0);
      } else if (cc == 2) {
        acc2 = __builtin_amdgcn_mfma_f32_16x16x32_bf16(ya0, w2f4, acc2, 0, 0, 0);
        acc2 = __builtin_amdgcn_mfma_f32_16x16x32_bf16(ya1, w2f5, acc2, 0, 0, 0);
      } else {
        acc2 = __builtin_amdgcn_mfma_f32_16x16x32_bf16(ya0, w2f6, acc2, 0, 0, 0);
        acc2 = __builtin_amdgcn_mfma_f32_16x16x32_bf16(ya1, w2f7, acc2, 0, 0, 0);
      }
    }
  }

  // epilogue: y2 = sigmoid(acc2 + b2) -> bf16 q/k/vT
  const int s   = l15;
  const int n   = (s & 1) * 2 + (r & 1);
  const int xsp = (s >> 1) * 8 + (r >> 1);
  const int bn  = b * 4 + n;
  uint16_t* qk = wsu + ((m == 0) ? QU_O : KU_O);
  uint16_t* vT = wsu + VT_O;
  #pragma unroll
  for (int p = 0; p < 4; ++p) {
    const int o = o_blk + lg * 4 + p;
    const uint16_t y2 = f2bf(sigmoid_f(acc2[p] + b2v));
    if (m == 2) vT[((size_t)bn * 64 + xsp) * 1024 + o] = y2;
    else        qk[((size_t)bn * 1024 + o) * 64 + xsp] = y2;
  }
}

// K3 (fused flash + in-block merge; VGPR-capped; R12 mapping bn=bid&7 —
// measured best of the two pin variants; pins themselves are a dead family).
__global__ __launch_bounds__(512, 4) void k3_attn(
    const uint16_t* __restrict__ qu, const uint16_t* __restrict__ ku,
    const uint16_t* __restrict__ vtu, const float* __restrict__ temp,
    float* __restrict__ out) {
  const int tid = threadIdx.x;
  const int wv  = tid >> 6;
  const int l   = tid & 63;
  const int l15 = l & 15, lg = l >> 4;
  const int bid = blockIdx.x;
  const int bn = bid & 7;
  const int ct = bid >> 3;
  const int cbase = ct * 16;
  const float tsc2 = temp[bn & 3] * 1.44269504089f;   // log2(e) folded

  __shared__ __align__(16) char SH[36864];
  uint16_t* pl  = (uint16_t*)SH + wv * 2304;   // per-wave P buffer
  float* poS = (float*)SH;                     // [8 waves][16 c][68] partial O^T
  float* mlS = poS + 8704;                     // [8 waves][32]: 16 m + 16 l

  const uint16_t* qrow = qu + (size_t)(bn * 1024 + cbase + l15) * 64 + lg * 8;
  const bf16x8 qf0 = *(const bf16x8*)(qrow);
  const bf16x8 qf1 = *(const bf16x8*)(qrow + 32);

  const uint16_t* kb = ku  + (size_t)bn * 65536 + lg * 8;
  const uint16_t* vb = vtu + (size_t)bn * 65536 + lg * 8;

  f32x4 o0 = {0.f,0.f,0.f,0.f}, o1 = o0, o2 = o0, o3 = o0;
  float mrun = -1.0e30f, lrun = 0.f;

  #pragma unroll
  for (int t = 0; t < 2; ++t) {
    const int e0 = wv * 128 + t * 64;

    // ---- K frags for this tile (32 VGPR, die after QK) ----
    const uint16_t* kr0 = kb + (size_t)(e0 +  0 + l15) * 64;
    const uint16_t* kr1 = kb + (size_t)(e0 + 16 + l15) * 64;
    const uint16_t* kr2 = kb + (size_t)(e0 + 32 + l15) * 64;
    const uint16_t* kr3 = kb + (size_t)(e0 + 48 + l15) * 64;
    const bf16x8 ka0 = *(const bf16x8*)(kr0);
    const bf16x8 kb0 = *(const bf16x8*)(kr0 + 32);
    const bf16x8 ka1 = *(const bf16x8*)(kr1);
    const bf16x8 kb1_ = *(const bf16x8*)(kr1 + 32);
    const bf16x8 ka2 = *(const bf16x8*)(kr2);
    const bf16x8 kb2_ = *(const bf16x8*)(kr2 + 32);
    const bf16x8 ka3 = *(const bf16x8*)(kr3);
    const bf16x8 kb3_ = *(const bf16x8*)(kr3 + 32);

    f32x4 s0 = {0.f,0.f,0.f,0.f}, s1 = s0, s2 = s0, s3 = s0;
    s0 = __builtin_amdgcn_mfma_f32_16x16x32_bf16(ka0, qf0, s0, 0,0,0);
    s0 = __builtin_amdgcn_mfma_f32_16x16x32_bf16(kb0, qf1, s0, 0,0,0);
    s1 = __builtin_amdgcn_mfma_f32_16x16x32_bf16(ka1, qf0, s1, 0,0,0);
    s1 = __builtin_amdgcn_mfma_f32_16x16x32_bf16(kb1_, qf1, s1, 0,0,0);
    s2 = __builtin_amdgcn_mfma_f32_16x16x32_bf16(ka2, qf0, s2, 0,0,0);
    s2 = __builtin_amdgcn_mfma_f32_16x16x32_bf16(kb2_, qf1, s2, 0,0,0);
    s3 = __builtin_amdgcn_mfma_f32_16x16x32_bf16(ka3, qf0, s3, 0,0,0);
    s3 = __builtin_amdgcn_mfma_f32_16x16x32_bf16(kb3_, qf1, s3, 0,0,0);

    // ---- V frags issue NOW (latency hides under softmax; reuse K's regs) ----
    const uint16_t* vr0 = vb + (size_t)( 0 + l15) * 1024 + e0;
    const uint16_t* vr1 = vb + (size_t)(16 + l15) * 1024 + e0;
    const uint16_t* vr2 = vb + (size_t)(32 + l15) * 1024 + e0;
    const uint16_t* vr3 = vb + (size_t)(48 + l15) * 1024 + e0;
    const bf16x8 v0a = *(const bf16x8*)(vr0);
    const bf16x8 v0b = *(const bf16x8*)(vr0 + 32);
    const bf16x8 v1a = *(const bf16x8*)(vr1);
    const bf16x8 v1b = *(const bf16x8*)(vr1 + 32);
    const bf16x8 v2a = *(const bf16x8*)(vr2);
    const bf16x8 v2b = *(const bf16x8*)(vr2 + 32);
    const bf16x8 v3a = *(const bf16x8*)(vr3);
    const bf16x8 v3b = *(const bf16x8*)(vr3 + 32);

    // ---- softmax in exp2 domain (per c = l15 column; lanes {l15+16g}) ----
    #pragma unroll
    for (int p = 0; p < 4; ++p) {
      s0[p] *= tsc2; s1[p] *= tsc2; s2[p] *= tsc2; s3[p] *= tsc2;
    }
    float t0 = fmaxf(fmaxf(s0[0], s0[1]), fmaxf(s0[2], s0[3]));
    float t1 = fmaxf(fmaxf(s1[0], s1[1]), fmaxf(s1[2], s1[3]));
    float t2 = fmaxf(fmaxf(s2[0], s2[1]), fmaxf(s2[2], s2[3]));
    float t3 = fmaxf(fmaxf(s3[0], s3[1]), fmaxf(s3[2], s3[3]));
    float tmax = fmaxf(fmaxf(t0, t1), fmaxf(t2, t3));
    tmax = fmaxf(tmax, __shfl_xor(tmax, 16, 64));
    tmax = fmaxf(tmax, __shfl_xor(tmax, 32, 64));
    const float mnew = fmaxf(mrun, tmax);
    const float scl  = exp2f(mrun - mnew);
    float psum = 0.f;
    #pragma unroll
    for (int p = 0; p < 4; ++p) { s0[p] = exp2f(s0[p] - mnew); psum += s0[p]; }
    #pragma unroll
    for (int p = 0; p < 4; ++p) { s1[p] = exp2f(s1[p] - mnew); psum += s1[p]; }
    #pragma unroll
    for (int p = 0; p < 4; ++p) { s2[p] = exp2f(s2[p] - mnew); psum += s2[p]; }
    #pragma unroll
    for (int p = 0; p < 4; ++p) { s3[p] = exp2f(s3[p] - mnew); psum += s3[p]; }
    psum += __shfl_xor(psum, 16, 64);
    psum += __shfl_xor(psum, 32, 64);
    lrun = lrun * scl + psum;
    mrun = mnew;

    // ---- pack P -> LDS [c][e] ----
    {
      uint32_t* p0w = (uint32_t*)&pl[l15 * 72 +  0 + lg * 4];
      uint32_t* p1w = (uint32_t*)&pl[l15 * 72 + 16 + lg * 4];
      uint32_t* p2w = (uint32_t*)&pl[l15 * 72 + 32 + lg * 4];
      uint32_t* p3w = (uint32_t*)&pl[l15 * 72 + 48 + lg * 4];
      p0w[0] = pk2bf(s0[0], s0[1]); p0w[1] = pk2bf(s0[2], s0[3]);
      p1w[0] = pk2bf(s1[0], s1[1]); p1w[1] = pk2bf(s1[2], s1[3]);
      p2w[0] = pk2bf(s2[0], s2[1]); p2w[1] = pk2bf(s2[2], s2[3]);
      p3w[0] = pk2bf(s3[0], s3[1]); p3w[1] = pk2bf(s3[2], s3[3]);
    }

    // ---- rescale O^T by scl (lane-local) ----
    #pragma unroll
    for (int p = 0; p < 4; ++p) {
      o0[p] *= scl; o1[p] *= scl; o2[p] *= scl; o3[p] *= scl;
    }

    // ---- PV: O^T[x][c] += sum_e V^T[x][e] P[e][c] ----
    {
      const bf16x8 pb0 = *(const bf16x8*)&pl[l15 * 72 +  0 + lg * 8];
      const bf16x8 pb1 = *(const bf16x8*)&pl[l15 * 72 + 32 + lg * 8];
      o0 = __builtin_amdgcn_mfma_f32_16x16x32_bf16(v0a, pb0, o0, 0,0,0);
      o0 = __builtin_amdgcn_mfma_f32_16x16x32_bf16(v0b, pb1, o0, 0,0,0);
      o1 = __builtin_amdgcn_mfma_f32_16x16x32_bf16(v1a, pb0, o1, 0,0,0);
      o1 = __builtin_amdgcn_mfma_f32_16x16x32_bf16(v1b, pb1, o1, 0,0,0);
      o2 = __builtin_amdgcn_mfma_f32_16x16x32_bf16(v2a, pb0, o2, 0,0,0);
      o2 = __builtin_amdgcn_mfma_f32_16x16x32_bf16(v2b, pb1, o2, 0,0,0);
      o3 = __builtin_amdgcn_mfma_f32_16x16x32_bf16(v3a, pb0, o3, 0,0,0);
      o3 = __builtin_amdgcn_mfma_f32_16x16x32_bf16(v3b, pb1, o3, 0,0,0);
    }
  }

  // ---- all waves done with P buffers before aliasing them ----
  __syncthreads();

  {
    float* po = poS + wv * 1088 + l15 * 68 + lg * 4;
    *(f32x4*)&po[ 0] = o0;
    *(f32x4*)&po[16] = o1;
    *(f32x4*)&po[32] = o2;
    *(f32x4*)&po[48] = o3;
    if (lg == 0) {
      mlS[wv * 32 + l15]      = mrun;
      mlS[wv * 32 + 16 + l15] = lrun;
    }
  }
  __syncthreads();

  // ---- merge: thread handles (c = tid>>5, x2 = (tid&31)*2, x2+1) ----
  {
    const int c  = tid >> 5;
    const int x2 = (tid & 31) * 2;

    float m0 = mlS[0 * 32 + c], m1 = mlS[1 * 32 + c];
    float m2 = mlS[2 * 32 + c], m3 = mlS[3 * 32 + c];
    float m4 = mlS[4 * 32 + c], m5 = mlS[5 * 32 + c];
    float m6 = mlS[6 * 32 + c], m7 = mlS[7 * 32 + c];
    const float M = fmaxf(fmaxf(fmaxf(m0, m1), fmaxf(m2, m3)),
                          fmaxf(fmaxf(m4, m5), fmaxf(m6, m7)));
    const float c0 = exp2f(m0 - M), c1 = exp2f(m1 - M);
    const float c2 = exp2f(m2 - M), c3 = exp2f(m3 - M);
    const float c4 = exp2f(m4 - M), c5 = exp2f(m5 - M);
    const float c6 = exp2f(m6 - M), c7 = exp2f(m7 - M);
    const float L = c0 * mlS[0 * 32 + 16 + c] + c1 * mlS[1 * 32 + 16 + c]
                  + c2 * mlS[2 * 32 + 16 + c] + c3 * mlS[3 * 32 + 16 + c]
                  + c4 * mlS[4 * 32 + 16 + c] + c5 * mlS[5 * 32 + 16 + c]
                  + c6 * mlS[6 * 32 + 16 + c] + c7 * mlS[7 * 32 + 16 + c];
    const float rl = __builtin_amdgcn_rcpf(L);

    const float* pb = poS + c * 68 + x2;
    float a0 = 0.f, a1 = 0.f;
    a0 += c0 * pb[0 * 1088]; a1 += c0 * pb[0 * 1088 + 1];
    a0 += c1 * pb[1 * 1088]; a1 += c1 * pb[1 * 1088 + 1];
    a0 += c2 * pb[2 * 1088]; a1 += c2 * pb[2 * 1088 + 1];
    a0 += c3 * pb[3 * 1088]; a1 += c3 * pb[3 * 1088 + 1];
    a0 += c4 * pb[4 * 1088]; a1 += c4 * pb[4 * 1088 + 1];
    a0 += c5 * pb[5 * 1088]; a1 += c5 * pb[5 * 1088 + 1];
    a0 += c6 * pb[6 * 1088]; a1 += c6 * pb[6 * 1088 + 1];
    a0 += c7 * pb[7 * 1088]; a1 += c7 * pb[7 * 1088 + 1];

    const int C = cbase + c;
    float* ob = out + ((size_t)bn * 256 + (C >> 2)) * 256 + (C & 3) * 64 + x2;
    ob[0] = a0 * rl;
    ob[1] = a1 * rl;
  }
}

extern "C" void kernel_launch(void* const* d_in, const int* in_sizes, int n_in,
                              void* d_out, int out_size, void* d_ws, size_t ws_size,
                              hipStream_t stream) {
  (void)in_sizes; (void)n_in; (void)out_size; (void)ws_size;
  const float* x      = (const float*)d_in[0];
  const float* conv_w = (const float*)d_in[1];
  const float* conv_b = (const float*)d_in[2];
  const float* qW1 = (const float*)d_in[3];
  const float* qb1 = (const float*)d_in[4];
  const float* qW2 = (const float*)d_in[5];
  const float* qb2 = (const float*)d_in[6];
  const float* kW1 = (const float*)d_in[7];
  const float* kb1 = (const float*)d_in[8];
  const float* kW2 = (const float*)d_in[9];
  const float* kb2 = (const float*)d_in[10];
  const float* vW1 = (const float*)d_in[11];
  const float* vb1 = (const float*)d_in[12];
  const float* vW2 = (const float*)d_in[13];
  const float* vb2 = (const float*)d_in[14];
  const float* temp = (const float*)d_in[15];
  float* wsf = (float*)d_ws;
  uint16_t* wsu = (uint16_t*)(wsf + U16_BASE_F);
  float* out = (float*)d_out;

  k1_G<<<dim3(1627), dim3(64), 0, stream>>>(x, qW1, kW1, vW1,
      conv_w, qW2, kW2, vW2, wsf, wsu);
  k2_mfma<<<dim3(1536), dim3(256), 0, stream>>>(
      wsu + GP_U, wsu + CW_U, wsu + W2T_U, conv_b,
      qb1, kb1, vb1, qb2, kb2, vb2, wsf, wsu);
  k3_attn<<<dim3(512), dim3(512), 0, stream>>>(
      wsu + QU_O, wsu + KU_O, wsu + VT_O, temp, out);
}

// Round 16
// 41.647 us; speedup vs baseline: 7.1221x; 1.1444x over previous
//
#include <hip/hip_runtime.h>
#include <cstdint>

constexpr int NB  = 2;     // batch
constexpr int NCI = 4;     // conv input channels
constexpr int NHH = 256;   // H
constexpr int NWW = 256;   // W
constexpr int NCT = 1024;  // conv output channels

// ---------------- workspace layout ----------------
constexpr size_t SW1F = 0;            // 48 floats
constexpr size_t U16_BASE_F = 48;     // u16 region starts here
// u16 offsets (relative to wsu):
constexpr size_t GP_U  = 0;           // G'bf [m][b][i][dx][r][258]
constexpr size_t CW_U  = 297216;      // CW_bf [o][40]
constexpr size_t W2T_U = 338176;      // W2T_bf [m][s][h]
constexpr size_t QU_O  = 350464;      // Q  bf16 [bn][o][xsp]
constexpr size_t KU_O  = 874752;      // K  bf16 [bn][o][xsp]
constexpr size_t VT_O  = 1399040;     // V^T bf16 [bn][xsp][o]

typedef __attribute__((ext_vector_type(8))) short bf16x8;
typedef __attribute__((ext_vector_type(4))) float f32x4;

__device__ __forceinline__ uint16_t f2bf(float x) {
  uint32_t u = __float_as_uint(x);
  return (uint16_t)((u + 0x7FFFu + ((u >> 16) & 1u)) >> 16);   // RNE
}
__device__ __forceinline__ uint32_t pk2bf(float a, float b) {  // lo=bf(a), hi=bf(b)
  const uint32_t au = __float_as_uint(a) + 0x8000u;
  const uint32_t bu = __float_as_uint(b) + 0x8000u;
  return __builtin_amdgcn_perm(bu, au, 0x07060302u);
}
__device__ __forceinline__ float sigmoid_f(float v) {
  return __builtin_amdgcn_rcpf(1.0f + __expf(-v));
}

// K1: G'bf[m][b][i][dx][r][1+h] = bf16( sum_w x_pad[b,i,h,w+dx-1] * W1_m[w,r] )
// (R15 parallelized prep kept.)
__global__ __launch_bounds__(64) void k1_G(
    const float* __restrict__ x,
    const float* __restrict__ qW1, const float* __restrict__ kW1,
    const float* __restrict__ vW1,
    const float* __restrict__ conv_w,
    const float* __restrict__ qW2, const float* __restrict__ kW2,
    const float* __restrict__ vW2,
    float* __restrict__ wsf, uint16_t* __restrict__ wsu) {
  const int tid = threadIdx.x;
  const int NBLK = 3 * NB * NCI * (NHH / 4);   // 1536
  int bid = blockIdx.x;

  if (bid >= NBLK + 3 + 64) {                  // W2T_bf prep (24 blocks)
    const int p = bid - (NBLK + 3 + 64);       // 0..23
    const int m = p >> 3;
    const int h0 = (p & 7) * 32;
    const float* W2 = (m == 0) ? qW2 : (m == 1) ? kW2 : vW2;
    const int hh = tid >> 1, part = tid & 1;   // 32 h x 2 halves
    const float* src = W2 + (size_t)(h0 + hh) * 16 + part * 8;
    const float4 a = *(const float4*)(src);
    const float4 b2 = *(const float4*)(src + 4);
    uint16_t* dst = wsu + W2T_U + (size_t)m * 4096 + h0 + hh;
    dst[(part * 8 + 0) * 256] = f2bf(a.x);
    dst[(part * 8 + 1) * 256] = f2bf(a.y);
    dst[(part * 8 + 2) * 256] = f2bf(a.z);
    dst[(part * 8 + 3) * 256] = f2bf(a.w);
    dst[(part * 8 + 4) * 256] = f2bf(b2.x);
    dst[(part * 8 + 5) * 256] = f2bf(b2.y);
    dst[(part * 8 + 6) * 256] = f2bf(b2.z);
    dst[(part * 8 + 7) * 256] = f2bf(b2.w);
    return;
  }
  if (bid >= NBLK + 3) {                       // CW_bf prep (64 blocks x 16 o)
    const int p = bid - (NBLK + 3);
    const int o = p * 16 + (tid >> 2);
    const int ks = (tid & 3) * 10;
    for (int u = 0; u < 10; ++u) {
      const int k = ks + u;
      wsu[CW_U + (size_t)o * 40 + k] = (k < 36) ? f2bf(conv_w[o * 36 + k]) : (uint16_t)0;
    }
    return;
  }
  if (bid >= NBLK) {                           // sw1 column sums (wave-parallel)
    const int m = bid - NBLK;
    const float* W1 = (m == 0) ? qW1 : (m == 1) ? kW1 : vW1;
    const int wc = tid >> 4, r = tid & 15;
    float s = 0.f;
    #pragma unroll 8
    for (int i = 0; i < 64; ++i) s += W1[(wc * 64 + i) * 16 + r];
    s += __shfl_xor(s, 16, 64);
    s += __shfl_xor(s, 32, 64);
    if (tid < 16) wsf[SW1F + m * 16 + tid] = s;
    return;
  }

  const int m  = bid / (NB * NCI * (NHH / 4));
  int rem      = bid % (NB * NCI * (NHH / 4));
  const int b  = rem / (NCI * (NHH / 4));
  rem          = rem % (NCI * (NHH / 4));
  const int i  = rem / (NHH / 4);
  const int h0 = (rem % (NHH / 4)) * 4;
  const int mb = m * NB + b;

  const float* W1 = (m == 0) ? qW1 : (m == 1) ? kW1 : vW1;

  __shared__ float W1l[16 * 260];
  __shared__ float xlb[4][260];

  for (int idx4 = tid; idx4 < 1024; idx4 += 64) {
    const float4 t = ((const float4*)W1)[idx4];
    const int w = idx4 >> 2, r0 = (idx4 & 3) * 4;
    W1l[(r0 + 0) * 260 + w] = t.x;
    W1l[(r0 + 1) * 260 + w] = t.y;
    W1l[(r0 + 2) * 260 + w] = t.z;
    W1l[(r0 + 3) * 260 + w] = t.w;
  }
  const float* xbase = x + ((size_t)(b * NCI + i) * NHH + h0) * NWW;
  for (int idx = tid; idx < 4 * 256; idx += 64) {
    const int rr = idx >> 8, w = idx & 255;
    xlb[rr][1 + w] = xbase[rr * NWW + w];
  }
  if (tid < 4) {
    xlb[tid][0] = 0.f; xlb[tid][257] = 0.f; xlb[tid][258] = 0.f; xlb[tid][259] = 0.f;
  }
  __syncthreads();

  // pad rows hp=0 and hp=257 (zeros)
  if (h0 == 0 && tid < 48) {
    const int dxp = tid >> 4, rp = tid & 15;
    wsu[GP_U + ((size_t)((mb * 4 + i) * 3 + dxp) * 16 + rp) * 258 + 0] = 0;
  }
  if (h0 == 252 && tid < 48) {
    const int dxp = tid >> 4, rp = tid & 15;
    wsu[GP_U + ((size_t)((mb * 4 + i) * 3 + dxp) * 16 + rp) * 258 + 257] = 0;
  }

  const int wc = tid >> 4, r = tid & 15;
  const int w0 = wc * 64;
  const size_t gb0 = GP_U + ((size_t)((mb * 4 + i) * 3 + 0) * 16 + r) * 258;

  #pragma unroll
  for (int rr = 0; rr < 4; ++rr) {
    const float* xl = xlb[rr];
    float a0 = 0.f, a1 = 0.f, a2 = 0.f;
    float4 cur = *(const float4*)&xl[w0];
    #pragma unroll 4
    for (int w = w0; w < w0 + 64; w += 4) {
      const float4 nxt = *(const float4*)&xl[w + 4];
      const float4 w1  = *(const float4*)&W1l[r * 260 + w];
      a0 += w1.x * cur.x + w1.y * cur.y + w1.z * cur.z + w1.w * cur.w;
      a1 += w1.x * cur.y + w1.y * cur.z + w1.z * cur.w + w1.w * nxt.x;
      a2 += w1.x * cur.z + w1.y * cur.w + w1.z * nxt.x + w1.w * nxt.y;
      cur = nxt;
    }
    a0 += __shfl_xor(a0, 16, 64); a0 += __shfl_xor(a0, 32, 64);
    a1 += __shfl_xor(a1, 16, 64); a1 += __shfl_xor(a1, 32, 64);
    a2 += __shfl_xor(a2, 16, 64); a2 += __shfl_xor(a2, 32, 64);
    if (wc == 0) {
      const int hp = 1 + h0 + rr;
      wsu[gb0 + hp]        = f2bf(a0);   // dx = 0
      wsu[gb0 + 4128 + hp] = f2bf(a1);   // dx = 1
      wsu[gb0 + 8256 + hp] = f2bf(a2);   // dx = 2
    }
  }
}

// K2 (MFMA): bf16 epilogue: Q,K [bn][o][xsp], V^T [bn][xsp][o].  (unchanged)
__global__ __launch_bounds__(256, 4) void k2_mfma(
    const uint16_t* __restrict__ gp, const uint16_t* __restrict__ cwbf,
    const uint16_t* __restrict__ w2t,
    const float* __restrict__ conv_b,
    const float* __restrict__ qb1, const float* __restrict__ kb1, const float* __restrict__ vb1,
    const float* __restrict__ qb2, const float* __restrict__ kb2, const float* __restrict__ vb2,
    const float* __restrict__ wsf, uint16_t* __restrict__ wsu) {
  const int tid = threadIdx.x;
  const int bid = blockIdx.x;
  const int r  = bid & 15;
  const int og = (bid >> 4) & 15;
  const int mb = bid >> 8;            // 0..5
  const int m  = mb >> 1, b = mb & 1;

  const int wv  = tid >> 6;
  const int l   = tid & 63;
  const int l15 = l & 15;
  const int lg  = l >> 4;

  __shared__ uint16_t GS[256 * 40];     // [h][k]
  __shared__ uint16_t y1l[4][16 * 72];  // per-wave [o16][h64+8pad]

  {
    const int h = tid;
    uint16_t* gsrow = &GS[h * 40];
    #pragma unroll
    for (int i = 0; i < 4; ++i) {
      #pragma unroll
      for (int dx = 0; dx < 3; ++dx) {
        const uint16_t* g = gp + ((size_t)((mb * 4 + i) * 3 + dx) * 16 + r) * 258 + h;
        gsrow[i * 9 + 0 * 3 + dx] = g[0];
        gsrow[i * 9 + 1 * 3 + dx] = g[1];
        gsrow[i * 9 + 2 * 3 + dx] = g[2];
      }
    }
    gsrow[36] = 0; gsrow[37] = 0; gsrow[38] = 0; gsrow[39] = 0;
  }
  __syncthreads();

  const float* b1 = (m == 0) ? qb1 : (m == 1) ? kb1 : vb1;
  const float* b2 = (m == 0) ? qb2 : (m == 1) ? kb2 : vb2;

  const int o_blk = og * 64 + wv * 16;

  const uint16_t* cwrow = cwbf + (size_t)(o_blk + l15) * 40;
  bf16x8 cw0 = *(const bf16x8*)(cwrow + lg * 8);
  bf16x8 cw1 = {0,0,0,0,0,0,0,0};
  if (lg == 0) cw1 = *(const bf16x8*)(cwrow + 32);

  const uint16_t* w2row = w2t + (size_t)m * 4096 + (size_t)l15 * 256 + lg * 8;
  bf16x8 w2f0 = *(const bf16x8*)(w2row + 0 * 32);
  bf16x8 w2f1 = *(const bf16x8*)(w2row + 1 * 32);
  bf16x8 w2f2 = *(const bf16x8*)(w2row + 2 * 32);
  bf16x8 w2f3 = *(const bf16x8*)(w2row + 3 * 32);
  bf16x8 w2f4 = *(const bf16x8*)(w2row + 4 * 32);
  bf16x8 w2f5 = *(const bf16x8*)(w2row + 5 * 32);
  bf16x8 w2f6 = *(const bf16x8*)(w2row + 6 * 32);
  bf16x8 w2f7 = *(const bf16x8*)(w2row + 7 * 32);

  const float sw1r = wsf[SW1F + m * 16 + r];
  const float b1r  = b1[r];
  const float cbv  = conv_b[o_blk + l15];
  const float bias1 = cbv * sw1r + b1r;
  const float b2v  = b2[l15];

  uint16_t* yw = &y1l[wv][0];
  f32x4 acc2 = {0.f, 0.f, 0.f, 0.f};

  #pragma unroll
  for (int cc = 0; cc < 4; ++cc) {
    #pragma unroll
    for (int ct = 0; ct < 4; ++ct) {
      const uint16_t* arow = &GS[(cc * 64 + ct * 16 + l15) * 40];
      bf16x8 a0 = *(const bf16x8*)(arow + lg * 8);
      bf16x8 a1 = {0,0,0,0,0,0,0,0};
      if (lg == 0) a1 = *(const bf16x8*)(arow + 32);
      f32x4 d = {0.f, 0.f, 0.f, 0.f};
      d = __builtin_amdgcn_mfma_f32_16x16x32_bf16(a0, cw0, d, 0, 0, 0);
      d = __builtin_amdgcn_mfma_f32_16x16x32_bf16(a1, cw1, d, 0, 0, 0);
      const float y0 = sigmoid_f(d[0] + bias1);
      const float y1 = sigmoid_f(d[1] + bias1);
      const float y2 = sigmoid_f(d[2] + bias1);
      const float y3 = sigmoid_f(d[3] + bias1);
      uint32_t* yd = (uint32_t*)&yw[l15 * 72 + ct * 16 + lg * 4];
      yd[0] = pk2bf(y0, y1);
      yd[1] = pk2bf(y2, y3);
    }
    {
      const uint16_t* yrow = &yw[l15 * 72 + lg * 8];
      bf16x8 ya0 = *(const bf16x8*)(yrow + 0);
      bf16x8 ya1 = *(const bf16x8*)(yrow + 32);
      if (cc == 0) {
        acc2 = __builtin_amdgcn_mfma_f32_16x16x32_bf16(ya0, w2f0, acc2, 0, 0, 0);
        acc2 = __builtin_amdgcn_mfma_f32_16x16x32_bf16(ya1, w2f1, acc2, 0, 0, 0);
      } else if (cc == 1) {
        acc2 = __builtin_amdgcn_mfma_f32_16x16x32_bf16(ya0, w2f2, acc2, 0, 0, 0);
        acc2 = __builtin_amdgcn_mfma_f32_16x16x32_bf16(ya1, w2f3, acc2, 0, 0, 0);
      } else if (cc == 2) {
        acc2 = __builtin_amdgcn_mfma_f32_16x16x32_bf16(ya0, w2f4, acc2, 0, 0, 0);
        acc2 = __builtin_amdgcn_mfma_f32_16x16x32_bf16(ya1, w2f5, acc2, 0, 0, 0);
      } else {
        acc2 = __builtin_amdgcn_mfma_f32_16x16x32_bf16(ya0, w2f6, acc2, 0, 0, 0);
        acc2 = __builtin_amdgcn_mfma_f32_16x16x32_bf16(ya1, w2f7, acc2, 0, 0, 0);
      }
    }
  }

  // epilogue: y2 = sigmoid(acc2 + b2) -> bf16 q/k/vT
  const int s   = l15;
  const int n   = (s & 1) * 2 + (r & 1);
  const int xsp = (s >> 1) * 8 + (r >> 1);
  const int bn  = b * 4 + n;
  uint16_t* qk = wsu + ((m == 0) ? QU_O : KU_O);
  uint16_t* vT = wsu + VT_O;
  #pragma unroll
  for (int p = 0; p < 4; ++p) {
    const int o = o_blk + lg * 4 + p;
    const uint16_t y2 = f2bf(sigmoid_f(acc2[p] + b2v));
    if (m == 2) vT[((size_t)bn * 64 + xsp) * 1024 + o] = y2;
    else        qk[((size_t)bn * 1024 + o) * 64 + xsp] = y2;
  }
}

// K3 (c=32 per block: halves logical K/V fetch — each K/V fragment feeds
// TWO c-tiles). grid 256 = 8 bn x 32 c-groups; block 512 = 8 waves; wave w
// owns e in [w*128, w*128+128) as 2 tiles of 64, both c-tiles per tile.
// In-block merge over 8 e-chunks x 2 c-tiles.
__global__ __launch_bounds__(512, 2) void k3_attn(
    const uint16_t* __restrict__ qu, const uint16_t* __restrict__ ku,
    const uint16_t* __restrict__ vtu, const float* __restrict__ temp,
    float* __restrict__ out) {
  const int tid = threadIdx.x;
  const int wv  = tid >> 6;
  const int l   = tid & 63;
  const int l15 = l & 15, lg = l >> 4;
  const int bid = blockIdx.x;
  const int bn = bid & 7;
  const int cg = bid >> 3;           // 0..31
  const int cbase = cg * 32;
  const float tsc2 = temp[bn & 3] * 1.44269504089f;   // log2(e) folded

  __shared__ __align__(16) char SH[71680];
  // P region (aliased under po): per (wave, ctile) 1152 u16
  uint16_t* plA = (uint16_t*)SH + (wv * 2 + 0) * 1152;
  uint16_t* plB = (uint16_t*)SH + (wv * 2 + 1) * 1152;
  float* poS = (float*)SH;                  // [16 (wv,ct)][16 c][68]
  float* mlS = poS + 17408;                 // [16 (wv,ct)][32]: 16 m + 16 l

  // Q frags for both c-tiles
  const uint16_t* qrowA = qu + (size_t)(bn * 1024 + cbase + l15) * 64 + lg * 8;
  const uint16_t* qrowB = qrowA + 16 * 64;
  const bf16x8 qf0a = *(const bf16x8*)(qrowA);
  const bf16x8 qf1a = *(const bf16x8*)(qrowA + 32);
  const bf16x8 qf0b = *(const bf16x8*)(qrowB);
  const bf16x8 qf1b = *(const bf16x8*)(qrowB + 32);

  const uint16_t* kb = ku  + (size_t)bn * 65536 + lg * 8;
  const uint16_t* vb = vtu + (size_t)bn * 65536 + lg * 8;

  f32x4 oa0 = {0.f,0.f,0.f,0.f}, oa1 = oa0, oa2 = oa0, oa3 = oa0;  // ct0 O^T
  f32x4 ob0 = oa0, ob1 = oa0, ob2 = oa0, ob3 = oa0;                // ct1 O^T
  float mrunA = -1.0e30f, lrunA = 0.f;
  float mrunB = -1.0e30f, lrunB = 0.f;

  #pragma unroll
  for (int t = 0; t < 2; ++t) {
    const int e0 = wv * 128 + t * 64;

    // ---- K frags (shared by both c-tiles; die after QK) ----
    const uint16_t* kr0 = kb + (size_t)(e0 +  0 + l15) * 64;
    const uint16_t* kr1 = kb + (size_t)(e0 + 16 + l15) * 64;
    const uint16_t* kr2 = kb + (size_t)(e0 + 32 + l15) * 64;
    const uint16_t* kr3 = kb + (size_t)(e0 + 48 + l15) * 64;
    const bf16x8 ka0 = *(const bf16x8*)(kr0);
    const bf16x8 kb0 = *(const bf16x8*)(kr0 + 32);
    const bf16x8 ka1 = *(const bf16x8*)(kr1);
    const bf16x8 kb1_ = *(const bf16x8*)(kr1 + 32);
    const bf16x8 ka2 = *(const bf16x8*)(kr2);
    const bf16x8 kb2_ = *(const bf16x8*)(kr2 + 32);
    const bf16x8 ka3 = *(const bf16x8*)(kr3);
    const bf16x8 kb3_ = *(const bf16x8*)(kr3 + 32);

    // QK^T for both c-tiles (16 mfma)
    f32x4 s0 = {0.f,0.f,0.f,0.f}, s1 = s0, s2 = s0, s3 = s0;   // ct0
    f32x4 u0 = s0, u1 = s0, u2 = s0, u3 = s0;                   // ct1
    s0 = __builtin_amdgcn_mfma_f32_16x16x32_bf16(ka0, qf0a, s0, 0,0,0);
    s0 = __builtin_amdgcn_mfma_f32_16x16x32_bf16(kb0, qf1a, s0, 0,0,0);
    s1 = __builtin_amdgcn_mfma_f32_16x16x32_bf16(ka1, qf0a, s1, 0,0,0);
    s1 = __builtin_amdgcn_mfma_f32_16x16x32_bf16(kb1_, qf1a, s1, 0,0,0);
    s2 = __builtin_amdgcn_mfma_f32_16x16x32_bf16(ka2, qf0a, s2, 0,0,0);
    s2 = __builtin_amdgcn_mfma_f32_16x16x32_bf16(kb2_, qf1a, s2, 0,0,0);
    s3 = __builtin_amdgcn_mfma_f32_16x16x32_bf16(ka3, qf0a, s3, 0,0,0);
    s3 = __builtin_amdgcn_mfma_f32_16x16x32_bf16(kb3_, qf1a, s3, 0,0,0);
    u0 = __builtin_amdgcn_mfma_f32_16x16x32_bf16(ka0, qf0b, u0, 0,0,0);
    u0 = __builtin_amdgcn_mfma_f32_16x16x32_bf16(kb0, qf1b, u0, 0,0,0);
    u1 = __builtin_amdgcn_mfma_f32_16x16x32_bf16(ka1, qf0b, u1, 0,0,0);
    u1 = __builtin_amdgcn_mfma_f32_16x16x32_bf16(kb1_, qf1b, u1, 0,0,0);
    u2 = __builtin_amdgcn_mfma_f32_16x16x32_bf16(ka2, qf0b, u2, 0,0,0);
    u2 = __builtin_amdgcn_mfma_f32_16x16x32_bf16(kb2_, qf1b, u2, 0,0,0);
    u3 = __builtin_amdgcn_mfma_f32_16x16x32_bf16(ka3, qf0b, u3, 0,0,0);
    u3 = __builtin_amdgcn_mfma_f32_16x16x32_bf16(kb3_, qf1b, u3, 0,0,0);

    // ---- V frags issue NOW (shared by both c-tiles; hide under 2x softmax) ----
    const uint16_t* vr0 = vb + (size_t)( 0 + l15) * 1024 + e0;
    const uint16_t* vr1 = vb + (size_t)(16 + l15) * 1024 + e0;
    const uint16_t* vr2 = vb + (size_t)(32 + l15) * 1024 + e0;
    const uint16_t* vr3 = vb + (size_t)(48 + l15) * 1024 + e0;
    const bf16x8 v0a = *(const bf16x8*)(vr0);
    const bf16x8 v0b = *(const bf16x8*)(vr0 + 32);
    const bf16x8 v1a = *(const bf16x8*)(vr1);
    const bf16x8 v1b = *(const bf16x8*)(vr1 + 32);
    const bf16x8 v2a = *(const bf16x8*)(vr2);
    const bf16x8 v2b = *(const bf16x8*)(vr2 + 32);
    const bf16x8 v3a = *(const bf16x8*)(vr3);
    const bf16x8 v3b = *(const bf16x8*)(vr3 + 32);

    // ---- softmax ct0 ----
    {
      #pragma unroll
      for (int p = 0; p < 4; ++p) {
        s0[p] *= tsc2; s1[p] *= tsc2; s2[p] *= tsc2; s3[p] *= tsc2;
      }
      float t0 = fmaxf(fmaxf(s0[0], s0[1]), fmaxf(s0[2], s0[3]));
      float t1 = fmaxf(fmaxf(s1[0], s1[1]), fmaxf(s1[2], s1[3]));
      float t2 = fmaxf(fmaxf(s2[0], s2[1]), fmaxf(s2[2], s2[3]));
      float t3 = fmaxf(fmaxf(s3[0], s3[1]), fmaxf(s3[2], s3[3]));
      float tmax = fmaxf(fmaxf(t0, t1), fmaxf(t2, t3));
      tmax = fmaxf(tmax, __shfl_xor(tmax, 16, 64));
      tmax = fmaxf(tmax, __shfl_xor(tmax, 32, 64));
      const float mnew = fmaxf(mrunA, tmax);
      const float scl  = exp2f(mrunA - mnew);
      float psum = 0.f;
      #pragma unroll
      for (int p = 0; p < 4; ++p) { s0[p] = exp2f(s0[p] - mnew); psum += s0[p]; }
      #pragma unroll
      for (int p = 0; p < 4; ++p) { s1[p] = exp2f(s1[p] - mnew); psum += s1[p]; }
      #pragma unroll
      for (int p = 0; p < 4; ++p) { s2[p] = exp2f(s2[p] - mnew); psum += s2[p]; }
      #pragma unroll
      for (int p = 0; p < 4; ++p) { s3[p] = exp2f(s3[p] - mnew); psum += s3[p]; }
      psum += __shfl_xor(psum, 16, 64);
      psum += __shfl_xor(psum, 32, 64);
      lrunA = lrunA * scl + psum;
      mrunA = mnew;
      uint32_t* p0w = (uint32_t*)&plA[l15 * 72 +  0 + lg * 4];
      uint32_t* p1w = (uint32_t*)&plA[l15 * 72 + 16 + lg * 4];
      uint32_t* p2w = (uint32_t*)&plA[l15 * 72 + 32 + lg * 4];
      uint32_t* p3w = (uint32_t*)&plA[l15 * 72 + 48 + lg * 4];
      p0w[0] = pk2bf(s0[0], s0[1]); p0w[1] = pk2bf(s0[2], s0[3]);
      p1w[0] = pk2bf(s1[0], s1[1]); p1w[1] = pk2bf(s1[2], s1[3]);
      p2w[0] = pk2bf(s2[0], s2[1]); p2w[1] = pk2bf(s2[2], s2[3]);
      p3w[0] = pk2bf(s3[0], s3[1]); p3w[1] = pk2bf(s3[2], s3[3]);
      #pragma unroll
      for (int p = 0; p < 4; ++p) {
        oa0[p] *= scl; oa1[p] *= scl; oa2[p] *= scl; oa3[p] *= scl;
      }
    }
    // ---- softmax ct1 ----
    {
      #pragma unroll
      for (int p = 0; p < 4; ++p) {
        u0[p] *= tsc2; u1[p] *= tsc2; u2[p] *= tsc2; u3[p] *= tsc2;
      }
      float t0 = fmaxf(fmaxf(u0[0], u0[1]), fmaxf(u0[2], u0[3]));
      float t1 = fmaxf(fmaxf(u1[0], u1[1]), fmaxf(u1[2], u1[3]));
      float t2 = fmaxf(fmaxf(u2[0], u2[1]), fmaxf(u2[2], u2[3]));
      float t3 = fmaxf(fmaxf(u3[0], u3[1]), fmaxf(u3[2], u3[3]));
      float tmax = fmaxf(fmaxf(t0, t1), fmaxf(t2, t3));
      tmax = fmaxf(tmax, __shfl_xor(tmax, 16, 64));
      tmax = fmaxf(tmax, __shfl_xor(tmax, 32, 64));
      const float mnew = fmaxf(mrunB, tmax);
      const float scl  = exp2f(mrunB - mnew);
      float psum = 0.f;
      #pragma unroll
      for (int p = 0; p < 4; ++p) { u0[p] = exp2f(u0[p] - mnew); psum += u0[p]; }
      #pragma unroll
      for (int p = 0; p < 4; ++p) { u1[p] = exp2f(u1[p] - mnew); psum += u1[p]; }
      #pragma unroll
      for (int p = 0; p < 4; ++p) { u2[p] = exp2f(u2[p] - mnew); psum += u2[p]; }
      #pragma unroll
      for (int p = 0; p < 4; ++p) { u3[p] = exp2f(u3[p] - mnew); psum += u3[p]; }
      psum += __shfl_xor(psum, 16, 64);
      psum += __shfl_xor(psum, 32, 64);
      lrunB = lrunB * scl + psum;
      mrunB = mnew;
      uint32_t* p0w = (uint32_t*)&plB[l15 * 72 +  0 + lg * 4];
      uint32_t* p1w = (uint32_t*)&plB[l15 * 72 + 16 + lg * 4];
      uint32_t* p2w = (uint32_t*)&plB[l15 * 72 + 32 + lg * 4];
      uint32_t* p3w = (uint32_t*)&plB[l15 * 72 + 48 + lg * 4];
      p0w[0] = pk2bf(u0[0], u0[1]); p0w[1] = pk2bf(u0[2], u0[3]);
      p1w[0] = pk2bf(u1[0], u1[1]); p1w[1] = pk2bf(u1[2], u1[3]);
      p2w[0] = pk2bf(u2[0], u2[1]); p2w[1] = pk2bf(u2[2], u2[3]);
      p3w[0] = pk2bf(u3[0], u3[1]); p3w[1] = pk2bf(u3[2], u3[3]);
      #pragma unroll
      for (int p = 0; p < 4; ++p) {
        ob0[p] *= scl; ob1[p] *= scl; ob2[p] *= scl; ob3[p] *= scl;
      }
    }

    // ---- PV for both c-tiles (16 mfma) ----
    {
      const bf16x8 pa0 = *(const bf16x8*)&plA[l15 * 72 +  0 + lg * 8];
      const bf16x8 pa1 = *(const bf16x8*)&plA[l15 * 72 + 32 + lg * 8];
      const bf16x8 pb0 = *(const bf16x8*)&plB[l15 * 72 +  0 + lg * 8];
      const bf16x8 pb1 = *(const bf16x8*)&plB[l15 * 72 + 32 + lg * 8];
      oa0 = __builtin_amdgcn_mfma_f32_16x16x32_bf16(v0a, pa0, oa0, 0,0,0);
      oa0 = __builtin_amdgcn_mfma_f32_16x16x32_bf16(v0b, pa1, oa0, 0,0,0);
      oa1 = __builtin_amdgcn_mfma_f32_16x16x32_bf16(v1a, pa0, oa1, 0,0,0);
      oa1 = __builtin_amdgcn_mfma_f32_16x16x32_bf16(v1b, pa1, oa1, 0,0,0);
      oa2 = __builtin_amdgcn_mfma_f32_16x16x32_bf16(v2a, pa0, oa2, 0,0,0);
      oa2 = __builtin_amdgcn_mfma_f32_16x16x32_bf16(v2b, pa1, oa2, 0,0,0);
      oa3 = __builtin_amdgcn_mfma_f32_16x16x32_bf16(v3a, pa0, oa3, 0,0,0);
      oa3 = __builtin_amdgcn_mfma_f32_16x16x32_bf16(v3b, pa1, oa3, 0,0,0);
      ob0 = __builtin_amdgcn_mfma_f32_16x16x32_bf16(v0a, pb0, ob0, 0,0,0);
      ob0 = __builtin_amdgcn_mfma_f32_16x16x32_bf16(v0b, pb1, ob0, 0,0,0);
      ob1 = __builtin_amdgcn_mfma_f32_16x16x32_bf16(v1a, pb0, ob1, 0,0,0);
      ob1 = __builtin_amdgcn_mfma_f32_16x16x32_bf16(v1b, pb1, ob1, 0,0,0);
      ob2 = __builtin_amdgcn_mfma_f32_16x16x32_bf16(v2a, pb0, ob2, 0,0,0);
      ob2 = __builtin_amdgcn_mfma_f32_16x16x32_bf16(v2b, pb1, ob2, 0,0,0);
      ob3 = __builtin_amdgcn_mfma_f32_16x16x32_bf16(v3a, pb0, ob3, 0,0,0);
      ob3 = __builtin_amdgcn_mfma_f32_16x16x32_bf16(v3b, pb1, ob3, 0,0,0);
    }
  }

  // ---- all waves done with P buffers before aliasing them ----
  __syncthreads();

  {
    float* poA = poS + (wv * 2 + 0) * 1088 + l15 * 68 + lg * 4;
    float* poB = poS + (wv * 2 + 1) * 1088 + l15 * 68 + lg * 4;
    *(f32x4*)&poA[ 0] = oa0;
    *(f32x4*)&poA[16] = oa1;
    *(f32x4*)&poA[32] = oa2;
    *(f32x4*)&poA[48] = oa3;
    *(f32x4*)&poB[ 0] = ob0;
    *(f32x4*)&poB[16] = ob1;
    *(f32x4*)&poB[32] = ob2;
    *(f32x4*)&poB[48] = ob3;
    if (lg == 0) {
      mlS[(wv * 2 + 0) * 32 + l15]      = mrunA;
      mlS[(wv * 2 + 0) * 32 + 16 + l15] = lrunA;
      mlS[(wv * 2 + 1) * 32 + l15]      = mrunB;
      mlS[(wv * 2 + 1) * 32 + 16 + l15] = lrunB;
    }
  }
  __syncthreads();

  // ---- merge: thread handles (c = tid>>4 in [0,32), x4 = (tid&15)*4) ----
  {
    const int c  = tid >> 4;
    const int x4 = (tid & 15) * 4;
    const int ctile = c >> 4, cl = c & 15;

    float mj[8], lj[8];
    #pragma unroll
    for (int j = 0; j < 8; ++j) {
      mj[j] = mlS[(j * 2 + ctile) * 32 + cl];
      lj[j] = mlS[(j * 2 + ctile) * 32 + 16 + cl];
    }
    float M = mj[0];
    #pragma unroll
    for (int j = 1; j < 8; ++j) M = fmaxf(M, mj[j]);
    float cj[8];
    float L = 0.f;
    #pragma unroll
    for (int j = 0; j < 8; ++j) { cj[j] = exp2f(mj[j] - M); L += cj[j] * lj[j]; }
    const float rl = __builtin_amdgcn_rcpf(L);

    float a0 = 0.f, a1 = 0.f, a2 = 0.f, a3 = 0.f;
    #pragma unroll
    for (int j = 0; j < 8; ++j) {
      const f32x4 pv = *(const f32x4*)&poS[(j * 2 + ctile) * 1088 + cl * 68 + x4];
      a0 += cj[j] * pv[0]; a1 += cj[j] * pv[1];
      a2 += cj[j] * pv[2]; a3 += cj[j] * pv[3];
    }

    const int C = cbase + c;
    float* ob = out + ((size_t)bn * 256 + (C >> 2)) * 256 + (C & 3) * 64 + x4;
    ob[0] = a0 * rl;
    ob[1] = a1 * rl;
    ob[2] = a2 * rl;
    ob[3] = a3 * rl;
  }
}

extern "C" void kernel_launch(void* const* d_in, const int* in_sizes, int n_in,
                              void* d_out, int out_size, void* d_ws, size_t ws_size,
                              hipStream_t stream) {
  (void)in_sizes; (void)n_in; (void)out_size; (void)ws_size;
  const float* x      = (const float*)d_in[0];
  const float* conv_w = (const float*)d_in[1];
  const float* conv_b = (const float*)d_in[2];
  const float* qW1 = (const float*)d_in[3];
  const float* qb1 = (const float*)d_in[4];
  const float* qW2 = (const float*)d_in[5];
  const float* qb2 = (const float*)d_in[6];
  const float* kW1 = (const float*)d_in[7];
  const float* kb1 = (const float*)d_in[8];
  const float* kW2 = (const float*)d_in[9];
  const float* kb2 = (const float*)d_in[10];
  const float* vW1 = (const float*)d_in[11];
  const float* vb1 = (const float*)d_in[12];
  const float* vW2 = (const float*)d_in[13];
  const float* vb2 = (const float*)d_in[14];
  const float* temp = (const float*)d_in[15];
  float* wsf = (float*)d_ws;
  uint16_t* wsu = (uint16_t*)(wsf + U16_BASE_F);
  float* out = (float*)d_out;

  k1_G<<<dim3(1627), dim3(64), 0, stream>>>(x, qW1, kW1, vW1,
      conv_w, qW2, kW2, vW2, wsf, wsu);
  k2_mfma<<<dim3(1536), dim3(256), 0, stream>>>(
      wsu + GP_U, wsu + CW_U, wsu + W2T_U, conv_b,
      qb1, kb1, vb1, qb2, kb2, vb2, wsf, wsu);
  k3_attn<<<dim3(256), dim3(512), 0, stream>>>(
      wsu + QU_O, wsu + KU_O, wsu + VT_O, temp, out);
}